// Round 2
// baseline (1036.425 us; speedup 1.0000x reference)
//
#include <hip/hip_runtime.h>

#define NPIX (512*512)

// JAX gelu(approximate=True): 0.5x(1+tanh(sqrt(2/pi)(x+0.044715x^3)))
// = x * sigmoid(2*sqrt(2/pi)*(x+0.044715x^3)); sigmoid via expf is inf-safe.
__device__ __forceinline__ float gelu_f(float x) {
    return x / (1.0f + __expf(-1.5957691216057308f * (x + 0.044715f * x * x * x)));
}

// ---------------------------------------------------------------------------
// Basis tables: Fb[n][m*2+ri] = (cos(2*pi*m*n/512), -sin(...))  (forward DFT)
//               Gb[n][o] = weight(m)/512 * Fb[n][o]             (inverse DFT)
// weight: 1 for m=0, 2 for m>=1 (Hermitian doubling); Im(X0) term has weight
// -sin(0)=0, matching irfft's discard of the DC imaginary part.
// ---------------------------------------------------------------------------
__global__ __launch_bounds__(256) void k_basis(float* __restrict__ Fb, float* __restrict__ Gb) {
    int id = blockIdx.x * 256 + threadIdx.x;   // 16384 = 512 * 32
    int n = id >> 5, o = id & 31, m = o >> 1, ri = o & 1;
    int k = (n * m) & 511;                     // exact angle reduction mod 512
    float ang = 6.283185307179586f * (1.0f / 512.0f) * (float)k;
    float sv, cv;
    sincosf(ang, &sv, &cv);
    float v = ri ? -sv : cv;
    Fb[id] = v;
    float w = (m == 0 ? 1.0f : 2.0f) * (1.0f / 512.0f);
    Gb[id] = w * v;
}

// Repack A_re/A_im [l][o][i][m][ax] -> Apk[l][ax][m][i][o][2] (coalesced mix staging)
// total elements: 4*2*16*64*64 = 524,288  (grid 2048 x 256)
__global__ __launch_bounds__(256) void k_apack(const float* __restrict__ Are,
                                               const float* __restrict__ Aim,
                                               float* __restrict__ Apk) {
    int id = blockIdx.x * 256 + threadIdx.x;
    if (id >= 524288) return;
    int o  = id & 63;
    int i  = (id >> 6) & 63;
    int m  = (id >> 12) & 15;
    int ax = (id >> 16) & 1;
    int l  = id >> 17;
    int src = (((l * 64 + o) * 64 + i) * 16 + m) * 2 + ax;
    Apk[2 * id]     = Are[src];
    Apk[2 * id + 1] = Aim[src];
}

// Encoder: h[p][pix] = We[p][0]*x0 + We[p][1]*x1 + We[p][2]*u + be[p]
__global__ __launch_bounds__(256) void k_enc(const float* __restrict__ u, const float* __restrict__ xc,
                                             const float* __restrict__ We, const float* __restrict__ be,
                                             float* __restrict__ h) {
    int pix = blockIdx.x * 256 + threadIdx.x;
    float x0 = xc[pix], x1 = xc[NPIX + pix], uu = u[pix];
    #pragma unroll 8
    for (int p = 0; p < 64; ++p) {
        h[(size_t)p * NPIX + pix] = We[p * 3] * x0 + We[p * 3 + 1] * x1 + We[p * 3 + 2] * uu + be[p];
    }
}

// Forward DFT along H (y): Vf_part[yh][p][w][o] = sum_{y in part} h[p][y][w]*Fb[y][o]
// grid(2, 64, 4) = (w-tile, p, y-quarter), block 256 (thread = w)
__global__ __launch_bounds__(256) void k_fwd_h(const float* __restrict__ h, const float* __restrict__ Fb,
                                               float* __restrict__ Vf) {
    __shared__ float fbl[128 * 32];
    int t = threadIdx.x;
    int wt = blockIdx.x, p = blockIdx.y, yh = blockIdx.z;
    int y0 = yh * 128;
    #pragma unroll
    for (int k = 0; k < 16; ++k) {
        int idx = t + k * 256;
        fbl[idx] = Fb[y0 * 32 + idx];
    }
    __syncthreads();
    int w = wt * 256 + t;
    float acc[32];
    #pragma unroll
    for (int o = 0; o < 32; ++o) acc[o] = 0.f;
    const float* hp = h + ((size_t)p * 512 + y0) * 512 + w;
    for (int y = 0; y < 128; ++y) {
        float v = hp[(size_t)y * 512];
        const float4* fr = (const float4*)&fbl[y * 32];
        #pragma unroll
        for (int k = 0; k < 8; ++k) {
            float4 f = fr[k];
            acc[4*k]   += v * f.x; acc[4*k+1] += v * f.y;
            acc[4*k+2] += v * f.z; acc[4*k+3] += v * f.w;
        }
    }
    float* out = Vf + ((size_t)(yh * 64 + p) * 512 + w) * 32;
    #pragma unroll
    for (int k = 0; k < 8; ++k) {
        float4 r; r.x = acc[4*k]; r.y = acc[4*k+1]; r.z = acc[4*k+2]; r.w = acc[4*k+3];
        ((float4*)out)[k] = r;
    }
}

// Forward DFT along W: Vf[(p*512+y)][o] = sum_w h[p][y][w]*Fb[w][o]
// 1024 blocks x 256; 32 rows/block; LDS-transposed tile, 4 rows per thread.
__global__ __launch_bounds__(256) void k_fwd_w(const float* __restrict__ h, const float* __restrict__ Fb,
                                               float* __restrict__ Vf) {
    __shared__ float tileT[128 * 36];          // [n][row], pad 36: aligned float4 + bank spread
    int t = threadIdx.x;
    int rowBase = blockIdx.x * 32;
    int o = t & 31, rq = t >> 5;
    float acc0 = 0.f, acc1 = 0.f, acc2 = 0.f, acc3 = 0.f;
    for (int nc = 0; nc < 4; ++nc) {
        __syncthreads();
        #pragma unroll
        for (int k = 0; k < 16; ++k) {
            int idx = t + k * 256;
            int nl = idx & 127, rl = idx >> 7;
            tileT[nl * 36 + rl] = h[(size_t)(rowBase + rl) * 512 + nc * 128 + nl];
        }
        __syncthreads();
        const float* fb = Fb + (nc * 128) * 32 + o;
        for (int n = 0; n < 128; ++n) {
            float4 rv = *(const float4*)&tileT[n * 36 + rq * 4];
            float bv = fb[n * 32];
            acc0 += rv.x * bv; acc1 += rv.y * bv; acc2 += rv.z * bv; acc3 += rv.w * bv;
        }
    }
    float* out = Vf + (size_t)(rowBase + rq * 4) * 32 + o;
    out[0] = acc0; out[32] = acc1; out[64] = acc2; out[96] = acc3;
}

// Mode mixing: Vm[o][other][m*2+ri] = sum_i A[o][i][m] (*) Vf[i][other][m]  (complex)
// grid 2048 (m = bid>>7, other-tile of 4 = bid&127), block 256 (o = t&63, j = t>>6)
__global__ __launch_bounds__(256) void k_mix(const float* __restrict__ Vf, int nparts,
                                             const float* __restrict__ Asl_base,
                                             float* __restrict__ Vm) {
    __shared__ float Aml[64 * 64 * 2];         // [i][o][2], 32KB
    __shared__ float Vfl[64 * 4 * 2];          // [i][j][2]
    int t = threadIdx.x;
    int m  = blockIdx.x >> 7;
    int ot = blockIdx.x & 127;
    const float4* Asl4 = (const float4*)(Asl_base + (size_t)m * 8192);
    #pragma unroll
    for (int k = 0; k < 8; ++k) {
        ((float4*)Aml)[t + k * 256] = Asl4[t + k * 256];
    }
    for (int q = t; q < 512; q += 256) {
        int i = q >> 3, jj = (q >> 1) & 3, ri = q & 1;
        float ssum = 0.f;
        for (int pt = 0; pt < nparts; ++pt)
            ssum += Vf[(((size_t)pt * 64 + i) * 512 + (ot * 4 + jj)) * 32 + m * 2 + ri];
        Vfl[q] = ssum;
    }
    __syncthreads();
    int o = t & 63, j = t >> 6;
    float re = 0.f, im = 0.f;
    #pragma unroll 4
    for (int i = 0; i < 64; ++i) {
        float2 a = *(const float2*)&Aml[(i * 64 + o) * 2];
        float2 v = *(const float2*)&Vfl[(i * 4 + j) * 2];
        re += a.x * v.x - a.y * v.y;
        im += a.x * v.y + a.y * v.x;
    }
    float2 r; r.x = re; r.y = im;
    *(float2*)(Vm + ((size_t)o * 512 + ot * 4 + j) * 32 + m * 2) = r;
}

// Fused inverse DFT (both axes), writes s (no RMW):
// s[p][y][w] = sum_o VmH[p][w][o]*Gb[y][o] + sum_o VmW[p][y][o]*Gb[w][o]
// grid(2, 64, 4) = (w-tile, p, y-quarter), block 256 (thread = w)
__global__ __launch_bounds__(256) void k_inv(const float* __restrict__ VmW, const float* __restrict__ VmH,
                                             const float* __restrict__ Gb, float* __restrict__ s) {
    __shared__ float gyl[128 * 32];
    __shared__ float vwl[128 * 32];
    int t = threadIdx.x;
    int wt = blockIdx.x, p = blockIdx.y, yq = blockIdx.z;
    int y0 = yq * 128;
    #pragma unroll
    for (int k = 0; k < 16; ++k) {
        int idx = t + k * 256;
        gyl[idx] = Gb[y0 * 32 + idx];
        vwl[idx] = VmW[((size_t)p * 512 + y0) * 32 + idx];
    }
    __syncthreads();
    int w = wt * 256 + t;
    float vh[32], gw[32];
    const float4* vhp = (const float4*)(VmH + ((size_t)p * 512 + w) * 32);
    const float4* gwp = (const float4*)(Gb + w * 32);
    #pragma unroll
    for (int k = 0; k < 8; ++k) {
        float4 a = vhp[k];
        vh[4*k] = a.x; vh[4*k+1] = a.y; vh[4*k+2] = a.z; vh[4*k+3] = a.w;
        float4 b = gwp[k];
        gw[4*k] = b.x; gw[4*k+1] = b.y; gw[4*k+2] = b.z; gw[4*k+3] = b.w;
    }
    float* sp = s + ((size_t)p * 512 + y0) * 512 + w;
    for (int y = 0; y < 128; ++y) {
        const float4* gy = (const float4*)&gyl[y * 32];
        const float4* vw = (const float4*)&vwl[y * 32];
        float acc = 0.f;
        #pragma unroll
        for (int k = 0; k < 8; ++k) {
            float4 g = gy[k], v = vw[k];
            acc += vh[4*k] * g.x + vh[4*k+1] * g.y + vh[4*k+2] * g.z + vh[4*k+3] * g.w;
            acc += gw[4*k] * v.x + gw[4*k+1] * v.y + gw[4*k+2] * v.z + gw[4*k+3] * v.w;
        }
        sp[(size_t)y * 512] = acc;
    }
}

// Fused FFN: h[o][pix] += gelu(W2 . gelu(W1 . s + b1) + b2), t-tile kept in LDS.
// 2048 blocks x 256; 128 pixels x 64 channels per block; thread = 4 pix x 8 outs.
__global__ __launch_bounds__(256) void k_ffn2(const float* __restrict__ in, float* __restrict__ out,
                                              const float* __restrict__ W1m, const float* __restrict__ b1v,
                                              const float* __restrict__ W2m, const float* __restrict__ b2v) {
    __shared__ float sW1[64 * 68];             // [c][o], pad 68: float4-aligned rows
    __shared__ float sW2[64 * 68];
    __shared__ float tile[16 * 128];           // input channel-slab staging
    __shared__ float tt[64 * 132];             // t tile [c][pix], pad 132 (float4-aligned)
    int t = threadIdx.x;
    int pixBase = blockIdx.x * 128;
    #pragma unroll
    for (int k = 0; k < 16; ++k) {
        int idx = t + k * 256;
        int c = idx & 63, o = idx >> 6;
        sW1[c * 68 + o] = W1m[o * 64 + c];
        sW2[c * 68 + o] = W2m[o * 64 + c];
    }
    int pl = (t & 31) * 4;
    int o8 = (t >> 5) * 8;
    float acc[8][4];
    #pragma unroll
    for (int j = 0; j < 8; ++j) { acc[j][0] = 0.f; acc[j][1] = 0.f; acc[j][2] = 0.f; acc[j][3] = 0.f; }
    for (int cb = 0; cb < 4; ++cb) {
        __syncthreads();
        #pragma unroll
        for (int k = 0; k < 8; ++k) {
            int idx = t + k * 256;             // 2048 = 16 ch x 128 pix
            int c = idx >> 7, pp = idx & 127;
            tile[c * 128 + pp] = in[(size_t)(cb * 16 + c) * NPIX + pixBase + pp];
        }
        __syncthreads();
        for (int c = 0; c < 16; ++c) {
            float4 av = *(const float4*)&tile[c * 128 + pl];
            const float4* wr = (const float4*)&sW1[(cb * 16 + c) * 68 + o8];
            float4 w0 = wr[0], w1 = wr[1];
            acc[0][0] += w0.x * av.x; acc[0][1] += w0.x * av.y; acc[0][2] += w0.x * av.z; acc[0][3] += w0.x * av.w;
            acc[1][0] += w0.y * av.x; acc[1][1] += w0.y * av.y; acc[1][2] += w0.y * av.z; acc[1][3] += w0.y * av.w;
            acc[2][0] += w0.z * av.x; acc[2][1] += w0.z * av.y; acc[2][2] += w0.z * av.z; acc[2][3] += w0.z * av.w;
            acc[3][0] += w0.w * av.x; acc[3][1] += w0.w * av.y; acc[3][2] += w0.w * av.z; acc[3][3] += w0.w * av.w;
            acc[4][0] += w1.x * av.x; acc[4][1] += w1.x * av.y; acc[4][2] += w1.x * av.z; acc[4][3] += w1.x * av.w;
            acc[5][0] += w1.y * av.x; acc[5][1] += w1.y * av.y; acc[5][2] += w1.y * av.z; acc[5][3] += w1.y * av.w;
            acc[6][0] += w1.z * av.x; acc[6][1] += w1.z * av.y; acc[6][2] += w1.z * av.z; acc[6][3] += w1.z * av.w;
            acc[7][0] += w1.w * av.x; acc[7][1] += w1.w * av.y; acc[7][2] += w1.w * av.z; acc[7][3] += w1.w * av.w;
        }
    }
    #pragma unroll
    for (int j = 0; j < 8; ++j) {
        float b = b1v[o8 + j];
        float4 r;
        r.x = gelu_f(acc[j][0] + b); r.y = gelu_f(acc[j][1] + b);
        r.z = gelu_f(acc[j][2] + b); r.w = gelu_f(acc[j][3] + b);
        *(float4*)&tt[(o8 + j) * 132 + pl] = r;
        acc[j][0] = 0.f; acc[j][1] = 0.f; acc[j][2] = 0.f; acc[j][3] = 0.f;
    }
    __syncthreads();
    for (int c = 0; c < 64; ++c) {
        float4 av = *(const float4*)&tt[c * 132 + pl];
        const float4* wr = (const float4*)&sW2[c * 68 + o8];
        float4 w0 = wr[0], w1 = wr[1];
        acc[0][0] += w0.x * av.x; acc[0][1] += w0.x * av.y; acc[0][2] += w0.x * av.z; acc[0][3] += w0.x * av.w;
        acc[1][0] += w0.y * av.x; acc[1][1] += w0.y * av.y; acc[1][2] += w0.y * av.z; acc[1][3] += w0.y * av.w;
        acc[2][0] += w0.z * av.x; acc[2][1] += w0.z * av.y; acc[2][2] += w0.z * av.z; acc[2][3] += w0.z * av.w;
        acc[3][0] += w0.w * av.x; acc[3][1] += w0.w * av.y; acc[3][2] += w0.w * av.z; acc[3][3] += w0.w * av.w;
        acc[4][0] += w1.x * av.x; acc[4][1] += w1.x * av.y; acc[4][2] += w1.x * av.z; acc[4][3] += w1.x * av.w;
        acc[5][0] += w1.y * av.x; acc[5][1] += w1.y * av.y; acc[5][2] += w1.y * av.z; acc[5][3] += w1.y * av.w;
        acc[6][0] += w1.z * av.x; acc[6][1] += w1.z * av.y; acc[6][2] += w1.z * av.z; acc[6][3] += w1.z * av.w;
        acc[7][0] += w1.w * av.x; acc[7][1] += w1.w * av.y; acc[7][2] += w1.w * av.z; acc[7][3] += w1.w * av.w;
    }
    #pragma unroll
    for (int j = 0; j < 8; ++j) {
        float b = b2v[o8 + j];
        float* op = out + (size_t)(o8 + j) * NPIX + pixBase + pl;
        float4 cur = *(const float4*)op;
        float4 r;
        r.x = cur.x + gelu_f(acc[j][0] + b); r.y = cur.y + gelu_f(acc[j][1] + b);
        r.z = cur.z + gelu_f(acc[j][2] + b); r.w = cur.w + gelu_f(acc[j][3] + b);
        *(float4*)op = r;
    }
}

// Decoder: out[pix] = sum_c Wd[c]*h[c][pix] + bd
__global__ __launch_bounds__(256) void k_dec(const float* __restrict__ h, const float* __restrict__ Wd,
                                             const float* __restrict__ bd, float* __restrict__ out) {
    int pix = blockIdx.x * 256 + threadIdx.x;
    float acc = bd[0];
    #pragma unroll 8
    for (int c = 0; c < 64; ++c) acc += Wd[c] * h[(size_t)c * NPIX + pix];
    out[pix] = acc;
}

extern "C" void kernel_launch(void* const* d_in, const int* in_sizes, int n_in,
                              void* d_out, int out_size, void* d_ws, size_t ws_size,
                              hipStream_t stream) {
    (void)in_sizes; (void)n_in; (void)out_size; (void)ws_size;
    const float* u   = (const float*)d_in[0];
    const float* xc  = (const float*)d_in[1];
    const float* We  = (const float*)d_in[2];
    const float* be  = (const float*)d_in[3];
    const float* W1  = (const float*)d_in[4];
    const float* b1  = (const float*)d_in[5];
    const float* W2  = (const float*)d_in[6];
    const float* b2  = (const float*)d_in[7];
    const float* Are = (const float*)d_in[8];
    const float* Aim = (const float*)d_in[9];
    const float* Wd  = (const float*)d_in[10];
    const float* bd  = (const float*)d_in[11];

    // workspace layout (floats), ~168 MB total
    float* ws  = (float*)d_ws;
    float* h   = ws;                            // 64 MB: [64][512][512]
    float* s   = h   + (size_t)16777216;        // 64 MB
    float* Vf  = s   + (size_t)16777216;        // 16 MB: 4 parts x [64][512][32]
    float* VmH = Vf  + (size_t)4194304;         // 4 MB
    float* VmW = VmH + (size_t)1048576;         // 4 MB
    float* Apk = VmW + (size_t)1048576;         // 8 MB: [l][ax][m][i][o][2]
    float* Fb  = Apk + (size_t)2097152;         // 64 KB
    float* Gb  = Fb  + (size_t)16384;           // 64 KB

    k_basis<<<64, 256, 0, stream>>>(Fb, Gb);
    k_apack<<<2048, 256, 0, stream>>>(Are, Aim, Apk);
    k_enc<<<1024, 256, 0, stream>>>(u, xc, We, be, h);

    for (int l = 0; l < 4; ++l) {
        // axis i=0 (H / y axis) uses A[..., 0]
        k_fwd_h<<<dim3(2, 64, 4), 256, 0, stream>>>(h, Fb, Vf);
        k_mix<<<2048, 256, 0, stream>>>(Vf, 4, Apk + (size_t)(l * 2 + 0) * 131072, VmH);
        // axis i=1 (W / x axis) uses A[..., 1]
        k_fwd_w<<<1024, 256, 0, stream>>>(h, Fb, Vf);
        k_mix<<<2048, 256, 0, stream>>>(Vf, 1, Apk + (size_t)(l * 2 + 1) * 131072, VmW);
        // fused inverse for both axes -> s
        k_inv<<<dim3(2, 64, 4), 256, 0, stream>>>(VmW, VmH, Gb, s);
        // fused FFN: h += gelu(W2 gelu(W1 s + b1) + b2)
        k_ffn2<<<2048, 256, 0, stream>>>(s, h, W1 + (size_t)l * 4096, b1 + (size_t)l * 64,
                                         W2 + (size_t)l * 4096, b2 + (size_t)l * 64);
    }
    k_dec<<<1024, 256, 0, stream>>>(h, Wd, bd, (float*)d_out);
}

// Round 3
// 904.368 us; speedup vs baseline: 1.1460x; 1.1460x over previous
//
#include <hip/hip_runtime.h>

#define NPIX (512*512)

typedef __attribute__((ext_vector_type(8))) short short8;   // 8 bf16 in 4 VGPRs
typedef __attribute__((ext_vector_type(4))) float f32x4;    // MFMA accumulator

// JAX gelu(approximate=True): x * sigmoid(2*sqrt(2/pi)*(x+0.044715x^3)); inf-safe.
__device__ __forceinline__ float gelu_f(float x) {
    return x / (1.0f + __expf(-1.5957691216057308f * (x + 0.044715f * x * x * x)));
}

// f32 -> bf16 bits (RNE)
__device__ __forceinline__ unsigned short bf16_rne(float x) {
    unsigned int b = __float_as_uint(x);
    unsigned int r = b + 0x7fffu + ((b >> 16) & 1u);
    return (unsigned short)(r >> 16);
}
__device__ __forceinline__ float bf16_tof(unsigned short h) {
    return __uint_as_float(((unsigned int)h) << 16);
}
// split x ~= hi + lo (each bf16); dropped cross term in 3-term MFMA ~2^-18 rel.
__device__ __forceinline__ unsigned int bf16_split_pack(float x) {
    unsigned short hi = bf16_rne(x);
    unsigned short lo = bf16_rne(x - bf16_tof(hi));
    return (unsigned int)hi | ((unsigned int)lo << 16);
}

// ---------------------------------------------------------------------------
// Basis tables: Fb[n][m*2+ri] = (cos(2*pi*m*n/512), -sin(...))  (forward DFT)
//               Gb[n][o] = weight(m)/512 * Fb[n][o]             (inverse DFT)
// ---------------------------------------------------------------------------
__global__ __launch_bounds__(256) void k_basis(float* __restrict__ Fb, float* __restrict__ Gb) {
    int id = blockIdx.x * 256 + threadIdx.x;   // 16384 = 512 * 32
    int n = id >> 5, o = id & 31, m = o >> 1, ri = o & 1;
    int k = (n * m) & 511;                     // exact angle reduction mod 512
    float ang = 6.283185307179586f * (1.0f / 512.0f) * (float)k;
    float sv, cv;
    sincosf(ang, &sv, &cv);
    float v = ri ? -sv : cv;
    Fb[id] = v;
    float w = (m == 0 ? 1.0f : 2.0f) * (1.0f / 512.0f);
    Gb[id] = w * v;
}

// Repack A_re/A_im [l][o][i][m][ax] -> Apk[l][ax][m][i][o][2]
__global__ __launch_bounds__(256) void k_apack(const float* __restrict__ Are,
                                               const float* __restrict__ Aim,
                                               float* __restrict__ Apk) {
    int id = blockIdx.x * 256 + threadIdx.x;
    if (id >= 524288) return;
    int o  = id & 63;
    int i  = (id >> 6) & 63;
    int m  = (id >> 12) & 15;
    int ax = (id >> 16) & 1;
    int l  = id >> 17;
    int src = (((l * 64 + o) * 64 + i) * 16 + m) * 2 + ax;
    Apk[2 * id]     = Are[src];
    Apk[2 * id + 1] = Aim[src];
}

// Pack FFN weights into MFMA A-fragment layout, split-bf16 hi/lo.
// Layout: [(layer*2+which)][s8=mt*2+kc][lane][16 shorts: hi[0..7], lo[0..7]]
// A-frag element j: W[mt*16 + (lane&15)][kc*32 + ((lane>>4)&3)*8 + j]
__global__ __launch_bounds__(256) void k_wpack(const float* __restrict__ W1, const float* __restrict__ W2,
                                               short* __restrict__ Wpk) {
    int tid = blockIdx.x * 256 + threadIdx.x;  // 4096 = 8 matrices * 4 mt * 2 kc * 64 lanes
    if (tid >= 4096) return;
    int lane = tid & 63;
    int kc = (tid >> 6) & 1;
    int mt = (tid >> 7) & 3;
    int wg = tid >> 9;                         // layer*2 + which
    int layer = wg >> 1, which = wg & 1;
    const float* Wsrc = (which ? W2 : W1) + (size_t)layer * 4096;
    int o  = mt * 16 + (lane & 15);
    int c0 = kc * 32 + ((lane >> 4) & 3) * 8;
    short* dst = Wpk + (size_t)tid * 16;
    #pragma unroll
    for (int j = 0; j < 8; ++j) {
        float x = Wsrc[o * 64 + c0 + j];
        unsigned short hi = bf16_rne(x);
        unsigned short lo = bf16_rne(x - bf16_tof(hi));
        dst[j]     = (short)hi;
        dst[8 + j] = (short)lo;
    }
}

// Encoder
__global__ __launch_bounds__(256) void k_enc(const float* __restrict__ u, const float* __restrict__ xc,
                                             const float* __restrict__ We, const float* __restrict__ be,
                                             float* __restrict__ h) {
    int pix = blockIdx.x * 256 + threadIdx.x;
    float x0 = xc[pix], x1 = xc[NPIX + pix], uu = u[pix];
    #pragma unroll 8
    for (int p = 0; p < 64; ++p) {
        h[(size_t)p * NPIX + pix] = We[p * 3] * x0 + We[p * 3 + 1] * x1 + We[p * 3 + 2] * uu + be[p];
    }
}

// Forward DFT along H (y)
__global__ __launch_bounds__(256) void k_fwd_h(const float* __restrict__ h, const float* __restrict__ Fb,
                                               float* __restrict__ Vf) {
    __shared__ float fbl[128 * 32];
    int t = threadIdx.x;
    int wt = blockIdx.x, p = blockIdx.y, yh = blockIdx.z;
    int y0 = yh * 128;
    #pragma unroll
    for (int k = 0; k < 16; ++k) {
        int idx = t + k * 256;
        fbl[idx] = Fb[y0 * 32 + idx];
    }
    __syncthreads();
    int w = wt * 256 + t;
    float acc[32];
    #pragma unroll
    for (int o = 0; o < 32; ++o) acc[o] = 0.f;
    const float* hp = h + ((size_t)p * 512 + y0) * 512 + w;
    for (int y = 0; y < 128; ++y) {
        float v = hp[(size_t)y * 512];
        const float4* fr = (const float4*)&fbl[y * 32];
        #pragma unroll
        for (int k = 0; k < 8; ++k) {
            float4 f = fr[k];
            acc[4*k]   += v * f.x; acc[4*k+1] += v * f.y;
            acc[4*k+2] += v * f.z; acc[4*k+3] += v * f.w;
        }
    }
    float* out = Vf + ((size_t)(yh * 64 + p) * 512 + w) * 32;
    #pragma unroll
    for (int k = 0; k < 8; ++k) {
        float4 r; r.x = acc[4*k]; r.y = acc[4*k+1]; r.z = acc[4*k+2]; r.w = acc[4*k+3];
        ((float4*)out)[k] = r;
    }
}

// Forward DFT along W
__global__ __launch_bounds__(256) void k_fwd_w(const float* __restrict__ h, const float* __restrict__ Fb,
                                               float* __restrict__ Vf) {
    __shared__ float tileT[128 * 36];
    int t = threadIdx.x;
    int rowBase = blockIdx.x * 32;
    int o = t & 31, rq = t >> 5;
    float acc0 = 0.f, acc1 = 0.f, acc2 = 0.f, acc3 = 0.f;
    for (int nc = 0; nc < 4; ++nc) {
        __syncthreads();
        #pragma unroll
        for (int k = 0; k < 16; ++k) {
            int idx = t + k * 256;
            int nl = idx & 127, rl = idx >> 7;
            tileT[nl * 36 + rl] = h[(size_t)(rowBase + rl) * 512 + nc * 128 + nl];
        }
        __syncthreads();
        const float* fb = Fb + (nc * 128) * 32 + o;
        for (int n = 0; n < 128; ++n) {
            float4 rv = *(const float4*)&tileT[n * 36 + rq * 4];
            float bv = fb[n * 32];
            acc0 += rv.x * bv; acc1 += rv.y * bv; acc2 += rv.z * bv; acc3 += rv.w * bv;
        }
    }
    float* out = Vf + (size_t)(rowBase + rq * 4) * 32 + o;
    out[0] = acc0; out[32] = acc1; out[64] = acc2; out[96] = acc3;
}

// Mode mixing (complex channel mix per retained mode)
__global__ __launch_bounds__(256) void k_mix(const float* __restrict__ Vf, int nparts,
                                             const float* __restrict__ Asl_base,
                                             float* __restrict__ Vm) {
    __shared__ float Aml[64 * 64 * 2];
    __shared__ float Vfl[64 * 4 * 2];
    int t = threadIdx.x;
    int m  = blockIdx.x >> 7;
    int ot = blockIdx.x & 127;
    const float4* Asl4 = (const float4*)(Asl_base + (size_t)m * 8192);
    #pragma unroll
    for (int k = 0; k < 8; ++k) {
        ((float4*)Aml)[t + k * 256] = Asl4[t + k * 256];
    }
    for (int q = t; q < 512; q += 256) {
        int i = q >> 3, jj = (q >> 1) & 3, ri = q & 1;
        float ssum = 0.f;
        for (int pt = 0; pt < nparts; ++pt)
            ssum += Vf[(((size_t)pt * 64 + i) * 512 + (ot * 4 + jj)) * 32 + m * 2 + ri];
        Vfl[q] = ssum;
    }
    __syncthreads();
    int o = t & 63, j = t >> 6;
    float re = 0.f, im = 0.f;
    #pragma unroll 4
    for (int i = 0; i < 64; ++i) {
        float2 a = *(const float2*)&Aml[(i * 64 + o) * 2];
        float2 v = *(const float2*)&Vfl[(i * 4 + j) * 2];
        re += a.x * v.x - a.y * v.y;
        im += a.x * v.y + a.y * v.x;
    }
    float2 r; r.x = re; r.y = im;
    *(float2*)(Vm + ((size_t)o * 512 + ot * 4 + j) * 32 + m * 2) = r;
}

// Fused inverse DFT (both axes) -> s
__global__ __launch_bounds__(256) void k_inv(const float* __restrict__ VmW, const float* __restrict__ VmH,
                                             const float* __restrict__ Gb, float* __restrict__ s) {
    __shared__ float gyl[128 * 32];
    __shared__ float vwl[128 * 32];
    int t = threadIdx.x;
    int wt = blockIdx.x, p = blockIdx.y, yq = blockIdx.z;
    int y0 = yq * 128;
    #pragma unroll
    for (int k = 0; k < 16; ++k) {
        int idx = t + k * 256;
        gyl[idx] = Gb[y0 * 32 + idx];
        vwl[idx] = VmW[((size_t)p * 512 + y0) * 32 + idx];
    }
    __syncthreads();
    int w = wt * 256 + t;
    float vh[32], gw[32];
    const float4* vhp = (const float4*)(VmH + ((size_t)p * 512 + w) * 32);
    const float4* gwp = (const float4*)(Gb + w * 32);
    #pragma unroll
    for (int k = 0; k < 8; ++k) {
        float4 a = vhp[k];
        vh[4*k] = a.x; vh[4*k+1] = a.y; vh[4*k+2] = a.z; vh[4*k+3] = a.w;
        float4 b = gwp[k];
        gw[4*k] = b.x; gw[4*k+1] = b.y; gw[4*k+2] = b.z; gw[4*k+3] = b.w;
    }
    float* sp = s + ((size_t)p * 512 + y0) * 512 + w;
    for (int y = 0; y < 128; ++y) {
        const float4* gy = (const float4*)&gyl[y * 32];
        const float4* vw = (const float4*)&vwl[y * 32];
        float acc = 0.f;
        #pragma unroll
        for (int k = 0; k < 8; ++k) {
            float4 g = gy[k], v = vw[k];
            acc += vh[4*k] * g.x + vh[4*k+1] * g.y + vh[4*k+2] * g.z + vh[4*k+3] * g.w;
            acc += gw[4*k] * v.x + gw[4*k+1] * v.y + gw[4*k+2] * v.z + gw[4*k+3] * v.w;
        }
        sp[(size_t)y * 512] = acc;
    }
}

// ---------------------------------------------------------------------------
// MFMA FFN: h[o][pix] += gelu(W2 . gelu(W1 . s + b1) + b2)
// Split-bf16 (hi+lo), 3-term MFMA products -> f32-grade accuracy at MFMA rate.
// Block = 256 thr (4 waves), 64-pixel tile; wave n-slice = 16 pix, full M=64.
// LDS: sT/tT are 64pix x 64c of u32 (hi|lo<<16), XOR-swizzled at 16B granule:
//   addr_u32(pix,c) = pix*64 + (((c>>2) ^ (pix&15))<<2) + (c&3)
// so transposed staging writes and B-frag b128 reads are both conflict-free.
// GEMM1 C-layout (col=lane&15 -> pix, row=quad*4+reg -> o) writes tT with one
// aligned b128 per (mt): the C->B layout transform costs zero extra passes.
// ---------------------------------------------------------------------------
__global__ __launch_bounds__(256, 2) void k_ffn2m(const float* __restrict__ in, float* __restrict__ out,
                                                  const short* __restrict__ w1f, const float* __restrict__ b1v,
                                                  const short* __restrict__ w2f, const float* __restrict__ b2v) {
    __shared__ __align__(16) unsigned int sT[64 * 64];
    __shared__ __align__(16) unsigned int tT[64 * 64];
    int t = threadIdx.x;
    int pixBase = blockIdx.x * 64;
    int lane15 = t & 15;
    int quad   = (t >> 4) & 3;
    int wv     = t >> 6;
    int row    = wv * 16 + lane15;           // this thread's pixel (col) in C-layout

    // ---- stage s tile: f32 -> split bf16 pack -> swizzled transposed LDS ----
    {
        int pp = t & 63;                      // pix
        int cq = wv;                          // wave id
        for (int q = 0; q < 4; ++q) {
            int cbase = q * 16 + cq * 4;
            unsigned int pk[4];
            #pragma unroll
            for (int i = 0; i < 4; ++i) {
                float x = in[(size_t)(cbase + i) * NPIX + pixBase + pp];
                pk[i] = bf16_split_pack(x);
            }
            int cg = cbase >> 2;
            unsigned int* dst = &sT[pp * 64 + (((cg ^ (pp & 15)) << 2))];
            *(uint4*)dst = make_uint4(pk[0], pk[1], pk[2], pk[3]);
        }
    }

    // ---- preload W1 A-frags (hi/lo) ----
    short8 W1h[8], W1l[8];
    #pragma unroll
    for (int s8 = 0; s8 < 8; ++s8) {
        const short8* p = (const short8*)(w1f + (((size_t)s8 * 64 + (t & 63)) << 4));
        W1h[s8] = p[0]; W1l[s8] = p[1];
    }

    f32x4 acc[4];
    #pragma unroll
    for (int mt = 0; mt < 4; ++mt) acc[mt] = (f32x4){0.f, 0.f, 0.f, 0.f};

    __syncthreads();

    // ---- GEMM1: t = W1 . s ----
    #pragma unroll
    for (int kc = 0; kc < 2; ++kc) {
        int cg0 = kc * 8 + quad * 2;
        uint4 u0 = *(const uint4*)&sT[row * 64 + ((cg0 ^ lane15) << 2)];
        uint4 u1 = *(const uint4*)&sT[row * 64 + (((cg0 + 1) ^ lane15) << 2)];
        union { unsigned int w[4]; short8 v; } bh, bl;
        bh.w[0] = (u0.x & 0xffffu) | (u0.y << 16);
        bh.w[1] = (u0.z & 0xffffu) | (u0.w << 16);
        bh.w[2] = (u1.x & 0xffffu) | (u1.y << 16);
        bh.w[3] = (u1.z & 0xffffu) | (u1.w << 16);
        bl.w[0] = (u0.x >> 16) | (u0.y & 0xffff0000u);
        bl.w[1] = (u0.z >> 16) | (u0.w & 0xffff0000u);
        bl.w[2] = (u1.x >> 16) | (u1.y & 0xffff0000u);
        bl.w[3] = (u1.z >> 16) | (u1.w & 0xffff0000u);
        #pragma unroll
        for (int mt = 0; mt < 4; ++mt) {
            int s8 = mt * 2 + kc;
            acc[mt] = __builtin_amdgcn_mfma_f32_16x16x32_bf16(W1h[s8], bh.v, acc[mt], 0, 0, 0);
            acc[mt] = __builtin_amdgcn_mfma_f32_16x16x32_bf16(W1h[s8], bl.v, acc[mt], 0, 0, 0);
            acc[mt] = __builtin_amdgcn_mfma_f32_16x16x32_bf16(W1l[s8], bh.v, acc[mt], 0, 0, 0);
        }
    }

    // ---- epilogue1: gelu, split, write tT (C-layout: 4 consecutive o per b128) ----
    #pragma unroll
    for (int mt = 0; mt < 4; ++mt) {
        const float* bp = b1v + mt * 16 + quad * 4;
        unsigned int pk[4];
        #pragma unroll
        for (int r = 0; r < 4; ++r) {
            float g = gelu_f(acc[mt][r] + bp[r]);
            pk[r] = bf16_split_pack(g);
        }
        int cg = mt * 4 + quad;
        unsigned int* dst = &tT[row * 64 + ((cg ^ lane15) << 2)];
        *(uint4*)dst = make_uint4(pk[0], pk[1], pk[2], pk[3]);
        acc[mt] = (f32x4){0.f, 0.f, 0.f, 0.f};
    }

    // ---- preload W2 A-frags ----
    short8 W2h[8], W2l[8];
    #pragma unroll
    for (int s8 = 0; s8 < 8; ++s8) {
        const short8* p = (const short8*)(w2f + (((size_t)s8 * 64 + (t & 63)) << 4));
        W2h[s8] = p[0]; W2l[s8] = p[1];
    }

    __syncthreads();

    // ---- GEMM2: W2 . t ----
    #pragma unroll
    for (int kc = 0; kc < 2; ++kc) {
        int cg0 = kc * 8 + quad * 2;
        uint4 u0 = *(const uint4*)&tT[row * 64 + ((cg0 ^ lane15) << 2)];
        uint4 u1 = *(const uint4*)&tT[row * 64 + (((cg0 + 1) ^ lane15) << 2)];
        union { unsigned int w[4]; short8 v; } bh, bl;
        bh.w[0] = (u0.x & 0xffffu) | (u0.y << 16);
        bh.w[1] = (u0.z & 0xffffu) | (u0.w << 16);
        bh.w[2] = (u1.x & 0xffffu) | (u1.y << 16);
        bh.w[3] = (u1.z & 0xffffu) | (u1.w << 16);
        bl.w[0] = (u0.x >> 16) | (u0.y & 0xffff0000u);
        bl.w[1] = (u0.z >> 16) | (u0.w & 0xffff0000u);
        bl.w[2] = (u1.x >> 16) | (u1.y & 0xffff0000u);
        bl.w[3] = (u1.z >> 16) | (u1.w & 0xffff0000u);
        #pragma unroll
        for (int mt = 0; mt < 4; ++mt) {
            int s8 = mt * 2 + kc;
            acc[mt] = __builtin_amdgcn_mfma_f32_16x16x32_bf16(W2h[s8], bh.v, acc[mt], 0, 0, 0);
            acc[mt] = __builtin_amdgcn_mfma_f32_16x16x32_bf16(W2h[s8], bl.v, acc[mt], 0, 0, 0);
            acc[mt] = __builtin_amdgcn_mfma_f32_16x16x32_bf16(W2l[s8], bh.v, acc[mt], 0, 0, 0);
        }
    }

    // ---- epilogue2: h += gelu(acc + b2) ----
    #pragma unroll
    for (int mt = 0; mt < 4; ++mt) {
        const float* bp = b2v + mt * 16 + quad * 4;
        #pragma unroll
        for (int r = 0; r < 4; ++r) {
            int o = mt * 16 + quad * 4 + r;
            size_t ga = (size_t)o * NPIX + pixBase + row;
            out[ga] = out[ga] + gelu_f(acc[mt][r] + bp[r]);
        }
    }
}

// Decoder
__global__ __launch_bounds__(256) void k_dec(const float* __restrict__ h, const float* __restrict__ Wd,
                                             const float* __restrict__ bd, float* __restrict__ out) {
    int pix = blockIdx.x * 256 + threadIdx.x;
    float acc = bd[0];
    #pragma unroll 8
    for (int c = 0; c < 64; ++c) acc += Wd[c] * h[(size_t)c * NPIX + pix];
    out[pix] = acc;
}

extern "C" void kernel_launch(void* const* d_in, const int* in_sizes, int n_in,
                              void* d_out, int out_size, void* d_ws, size_t ws_size,
                              hipStream_t stream) {
    (void)in_sizes; (void)n_in; (void)out_size; (void)ws_size;
    const float* u   = (const float*)d_in[0];
    const float* xc  = (const float*)d_in[1];
    const float* We  = (const float*)d_in[2];
    const float* be  = (const float*)d_in[3];
    const float* W1  = (const float*)d_in[4];
    const float* b1  = (const float*)d_in[5];
    const float* W2  = (const float*)d_in[6];
    const float* b2  = (const float*)d_in[7];
    const float* Are = (const float*)d_in[8];
    const float* Aim = (const float*)d_in[9];
    const float* Wd  = (const float*)d_in[10];
    const float* bd  = (const float*)d_in[11];

    // workspace layout (floats), ~168 MB total
    float* ws  = (float*)d_ws;
    float* h   = ws;                            // 64 MB: [64][512][512]
    float* s   = h   + (size_t)16777216;        // 64 MB
    float* Vf  = s   + (size_t)16777216;        // 16 MB: 4 parts x [64][512][32]
    float* VmH = Vf  + (size_t)4194304;         // 4 MB
    float* VmW = VmH + (size_t)1048576;         // 4 MB
    float* Apk = VmW + (size_t)1048576;         // 8 MB: [l][ax][m][i][o][2]
    float* Fb  = Apk + (size_t)2097152;         // 64 KB
    float* Gb  = Fb  + (size_t)16384;           // 64 KB
    short* Wpk = (short*)(Gb + 16384);          // 128 KB: packed FFN weight frags

    k_basis<<<64, 256, 0, stream>>>(Fb, Gb);
    k_apack<<<2048, 256, 0, stream>>>(Are, Aim, Apk);
    k_wpack<<<16, 256, 0, stream>>>(W1, W2, Wpk);
    k_enc<<<1024, 256, 0, stream>>>(u, xc, We, be, h);

    for (int l = 0; l < 4; ++l) {
        // axis i=0 (H / y axis) uses A[..., 0]
        k_fwd_h<<<dim3(2, 64, 4), 256, 0, stream>>>(h, Fb, Vf);
        k_mix<<<2048, 256, 0, stream>>>(Vf, 4, Apk + (size_t)(l * 2 + 0) * 131072, VmH);
        // axis i=1 (W / x axis) uses A[..., 1]
        k_fwd_w<<<1024, 256, 0, stream>>>(h, Fb, Vf);
        k_mix<<<2048, 256, 0, stream>>>(Vf, 1, Apk + (size_t)(l * 2 + 1) * 131072, VmW);
        // fused inverse for both axes -> s
        k_inv<<<dim3(2, 64, 4), 256, 0, stream>>>(VmW, VmH, Gb, s);
        // fused MFMA FFN: h += gelu(W2 gelu(W1 s + b1) + b2)
        k_ffn2m<<<4096, 256, 0, stream>>>(s, h,
                                          Wpk + (size_t)(l * 2 + 0) * 8192, b1 + (size_t)l * 64,
                                          Wpk + (size_t)(l * 2 + 1) * 8192, b2 + (size_t)l * 64);
    }
    k_dec<<<1024, 256, 0, stream>>>(h, Wd, bd, (float*)d_out);
}

// Round 4
// 644.574 us; speedup vs baseline: 1.6079x; 1.4030x over previous
//
#include <hip/hip_runtime.h>

#define NPIX (512*512)

typedef __attribute__((ext_vector_type(8))) short short8;   // 8 bf16 in 4 VGPRs
typedef __attribute__((ext_vector_type(4))) float f32x4;    // MFMA accumulator

#define MFMA16(A, B, C) __builtin_amdgcn_mfma_f32_16x16x32_bf16((A), (B), (C), 0, 0, 0)

// JAX gelu(approximate=True): x * sigmoid(2*sqrt(2/pi)*(x+0.044715x^3)); inf-safe.
__device__ __forceinline__ float gelu_f(float x) {
    return x / (1.0f + __expf(-1.5957691216057308f * (x + 0.044715f * x * x * x)));
}

// f32 -> bf16 bits (RNE)
__device__ __forceinline__ unsigned short bf16_rne(float x) {
    unsigned int b = __float_as_uint(x);
    unsigned int r = b + 0x7fffu + ((b >> 16) & 1u);
    return (unsigned short)(r >> 16);
}
__device__ __forceinline__ float bf16_tof(unsigned short h) {
    return __uint_as_float(((unsigned int)h) << 16);
}
// split x ~= hi + lo (each bf16); dropped cross term in 3-term MFMA ~2^-18 rel.
__device__ __forceinline__ unsigned int bf16_split_pack(float x) {
    unsigned short hi = bf16_rne(x);
    unsigned short lo = bf16_rne(x - bf16_tof(hi));
    return (unsigned int)hi | ((unsigned int)lo << 16);
}
__device__ __forceinline__ void split8(const float* x, short8& h, short8& l) {
    #pragma unroll
    for (int j = 0; j < 8; ++j) {
        unsigned short hi = bf16_rne(x[j]);
        h[j] = (short)hi;
        l[j] = (short)bf16_rne(x[j] - bf16_tof(hi));
    }
}

// ---------------------------------------------------------------------------
// Packed DFT basis tables (split-bf16 frag records: 16 shorts = hi[8] | lo[8]).
// FbB (forward basis): record (kc<16, nt<2, lane): elem j = Fb[kc*32+quad*8+j][nt*16+l15]
//   where Fb[n][o]: m=o>>1, ri=o&1, val = ri ? -sin : cos (2*pi*(n*m mod 512)/512).
//   Serves as A-frag (m=o) for BOTH forward DFTs (A-frag of Fb^T == B-frag of Fb).
// GbF (inverse basis): record (t<32, lane): elem j = Gb[t*16+l15][quad*8+j]
//   where Gb[n][o] = wt(m)/512 * Fb[n][o], wt = (m==0?1:2).
//   Serves as A-frag (m=y, G1) and B-frag (k=o, G2) of the fused inverse.
// ---------------------------------------------------------------------------
__global__ __launch_bounds__(256) void k_bpack(short* __restrict__ FbB, short* __restrict__ GbF) {
    int id = blockIdx.x * 256 + threadIdx.x;   // 4096 records
    int lane = id & 63;
    int quad = lane >> 4, l15 = lane & 15;
    short* dst;
    int n0, nstep, o0, ostep;
    float wscale = 1.0f;
    if (id < 2048) {                            // FbB: n = y/w (k-dim), o = mode col
        int nt = (id >> 6) & 1, kc = id >> 7;
        dst = FbB + id * 16;
        n0 = kc * 32 + quad * 8; nstep = 1;     // n varies with j
        o0 = nt * 16 + l15;      ostep = 0;
    } else {                                    // GbF: n = y/w (m-dim), o varies with j
        int id2 = id - 2048;
        dst = GbF + id2 * 16;
        int t = id2 >> 6;
        n0 = t * 16 + l15;       nstep = 0;
        o0 = quad * 8;           ostep = 1;
        wscale = 1.0f / 512.0f;
    }
    #pragma unroll
    for (int j = 0; j < 8; ++j) {
        int n = n0 + nstep * j;
        int o = o0 + ostep * j;
        int m = o >> 1, ri = o & 1;
        int k = (n * m) & 511;
        float sv, cv;
        sincosf(6.283185307179586f * (1.0f / 512.0f) * (float)k, &sv, &cv);
        float v = ri ? -sv : cv;
        if (id >= 2048) v *= (m == 0 ? 1.0f : 2.0f) * wscale;
        unsigned short hi = bf16_rne(v);
        dst[j]     = (short)hi;
        dst[8 + j] = (short)bf16_rne(v - bf16_tof(hi));
    }
}

// Pack spectral weights A into mix A-frag records of 48 shorts:
// [Ar_h8|Ar_l8|Ai_h8|Ai_l8|An_h8|An_l8] (An = -Ai, avoids MFMA subtraction).
// Record (l<4, ax<2, m<16, mt<4, kc<2, lane<64): o = mt*16+l15, i = kc*32+quad*8+j.
__global__ __launch_bounds__(256) void k_afrag(const float* __restrict__ Are,
                                               const float* __restrict__ Aim,
                                               short* __restrict__ Am) {
    int id = blockIdx.x * 256 + threadIdx.x;   // 65536 records
    int lane = id & 63;
    int kc  = (id >> 6) & 1;
    int mt  = (id >> 7) & 3;
    int m   = (id >> 9) & 15;
    int lax = id >> 13;
    int l = lax >> 1, ax = lax & 1;
    int o  = mt * 16 + (lane & 15);
    int i0 = kc * 32 + ((lane >> 4) & 3) * 8;
    short* dst = Am + (size_t)id * 48;
    #pragma unroll
    for (int j = 0; j < 8; ++j) {
        size_t src = (((size_t)(l * 64 + o) * 64 + (i0 + j)) * 16 + m) * 2 + ax;
        float ar = Are[src], ai = Aim[src];
        unsigned short h;
        h = bf16_rne(ar);  dst[j]      = (short)h; dst[8 + j]  = (short)bf16_rne(ar - bf16_tof(h));
        h = bf16_rne(ai);  dst[16 + j] = (short)h; dst[24 + j] = (short)bf16_rne(ai - bf16_tof(h));
        h = bf16_rne(-ai); dst[32 + j] = (short)h; dst[40 + j] = (short)bf16_rne(-ai - bf16_tof(h));
    }
}

// Pack FFN weights into MFMA A-frag layout, split-bf16 hi/lo.
__global__ __launch_bounds__(256) void k_wpack(const float* __restrict__ W1, const float* __restrict__ W2,
                                               short* __restrict__ Wpk) {
    int tid = blockIdx.x * 256 + threadIdx.x;  // 4096 = 8 matrices * 4 mt * 2 kc * 64 lanes
    if (tid >= 4096) return;
    int lane = tid & 63;
    int kc = (tid >> 6) & 1;
    int mt = (tid >> 7) & 3;
    int wg = tid >> 9;
    int layer = wg >> 1, which = wg & 1;
    const float* Wsrc = (which ? W2 : W1) + (size_t)layer * 4096;
    int o  = mt * 16 + (lane & 15);
    int c0 = kc * 32 + ((lane >> 4) & 3) * 8;
    short* dst = Wpk + (size_t)tid * 16;
    #pragma unroll
    for (int j = 0; j < 8; ++j) {
        float x = Wsrc[o * 64 + c0 + j];
        unsigned short hi = bf16_rne(x);
        dst[j]     = (short)hi;
        dst[8 + j] = (short)bf16_rne(x - bf16_tof(hi));
    }
}

// Encoder
__global__ __launch_bounds__(256) void k_enc(const float* __restrict__ u, const float* __restrict__ xc,
                                             const float* __restrict__ We, const float* __restrict__ be,
                                             float* __restrict__ h) {
    int pix = blockIdx.x * 256 + threadIdx.x;
    float x0 = xc[pix], x1 = xc[NPIX + pix], uu = u[pix];
    #pragma unroll 8
    for (int p = 0; p < 64; ++p) {
        h[(size_t)p * NPIX + pix] = We[p * 3] * x0 + We[p * 3 + 1] * x1 + We[p * 3 + 2] * uu + be[p];
    }
}

// ---------------------------------------------------------------------------
// Forward DFT along H (y): Vf[part][p][o][w] = sum_{y in part} Fb[y][o]*h[p][y][w]
// D[m=o][n=w]; A = FbB table; B = h columns (8 stride-512 loads, coalesced per
// instruction: 4 quads x 16 consecutive lanes x 4B = 4x64B). No LDS.
// grid(8 wtile, 64 p, 4 part), block 256: wave -> 16-w n-slice.
// ---------------------------------------------------------------------------
__global__ __launch_bounds__(256) void k_fwd_h(const float* __restrict__ h, const short* __restrict__ FbB,
                                               float* __restrict__ Vf) {
    int t = threadIdx.x;
    int wt = blockIdx.x, p = blockIdx.y, part = blockIdx.z;
    int wv = t >> 6, lane = t & 63, quad = lane >> 4, l15 = lane & 15;
    int w = wt * 64 + wv * 16 + l15;
    f32x4 acc[2];
    acc[0] = (f32x4){0.f,0.f,0.f,0.f}; acc[1] = (f32x4){0.f,0.f,0.f,0.f};
    #pragma unroll
    for (int kc = 0; kc < 4; ++kc) {
        int yb = part * 128 + kc * 32 + quad * 8;
        const float* hp = h + ((size_t)p * 512 + yb) * 512 + w;
        float bv[8];
        #pragma unroll
        for (int j = 0; j < 8; ++j) bv[j] = hp[(size_t)j * 512];
        short8 Bh, Bl; split8(bv, Bh, Bl);
        int kidx = part * 4 + kc;
        #pragma unroll
        for (int mt = 0; mt < 2; ++mt) {
            const short8* ap = (const short8*)(FbB + (((kidx * 2 + mt) * 64 + lane) << 4));
            short8 Ah = ap[0], Al = ap[1];
            acc[mt] = MFMA16(Ah, Bh, acc[mt]);
            acc[mt] = MFMA16(Al, Bh, acc[mt]);
            acc[mt] = MFMA16(Ah, Bl, acc[mt]);
        }
    }
    float* vp = Vf + ((size_t)(part * 64 + p) * 32) * 512;
    #pragma unroll
    for (int mt = 0; mt < 2; ++mt)
        #pragma unroll
        for (int r = 0; r < 4; ++r)
            vp[(size_t)(mt * 16 + quad * 4 + r) * 512 + w] = acc[mt][r];
}

// Forward DFT along W: Vf[part][p][o][y] = sum_{w in part} Fb[w][o]*h[p][y][w]
// D[m=o][n=y]; A = FbB table; B = h rows (2 x dwordx4). No LDS.
// grid(8 ytile, 64 p, 4 part), block 256: wave -> 16-y n-slice.
__global__ __launch_bounds__(256) void k_fwd_w(const float* __restrict__ h, const short* __restrict__ FbB,
                                               float* __restrict__ Vf) {
    int t = threadIdx.x;
    int yt = blockIdx.x, p = blockIdx.y, part = blockIdx.z;
    int wv = t >> 6, lane = t & 63, quad = lane >> 4, l15 = lane & 15;
    int y = yt * 64 + wv * 16 + l15;
    f32x4 acc[2];
    acc[0] = (f32x4){0.f,0.f,0.f,0.f}; acc[1] = (f32x4){0.f,0.f,0.f,0.f};
    #pragma unroll
    for (int kc = 0; kc < 4; ++kc) {
        int wb = part * 128 + kc * 32 + quad * 8;
        const float* hp = h + ((size_t)p * 512 + y) * 512 + wb;
        float bv[8];
        float4 x0 = *(const float4*)hp;
        float4 x1 = *(const float4*)(hp + 4);
        bv[0]=x0.x; bv[1]=x0.y; bv[2]=x0.z; bv[3]=x0.w;
        bv[4]=x1.x; bv[5]=x1.y; bv[6]=x1.z; bv[7]=x1.w;
        short8 Bh, Bl; split8(bv, Bh, Bl);
        int kidx = part * 4 + kc;
        #pragma unroll
        for (int mt = 0; mt < 2; ++mt) {
            const short8* ap = (const short8*)(FbB + (((kidx * 2 + mt) * 64 + lane) << 4));
            short8 Ah = ap[0], Al = ap[1];
            acc[mt] = MFMA16(Ah, Bh, acc[mt]);
            acc[mt] = MFMA16(Al, Bh, acc[mt]);
            acc[mt] = MFMA16(Ah, Bl, acc[mt]);
        }
    }
    float* vp = Vf + ((size_t)(part * 64 + p) * 32) * 512;
    #pragma unroll
    for (int mt = 0; mt < 2; ++mt)
        #pragma unroll
        for (int r = 0; r < 4; ++r)
            vp[(size_t)(mt * 16 + quad * 4 + r) * 512 + y] = acc[mt][r];
}

// ---------------------------------------------------------------------------
// Mode mixing (complex): Vm[o][oth][m*2+ri]; D_re = Ar.Br + An.Bi, D_im = Ar.Bi + Ai.Br.
// grid 256 (m = bid&15, otile = bid>>4 of 32 others), block 256.
// B tile: part-summed Vf -> split-packed u32 LDS [ri][i 64][oth 32+pad].
// wave -> (nt = wv&1, mt pair = wv>>1); K = i (2 ksteps).
// ---------------------------------------------------------------------------
__global__ __launch_bounds__(256) void k_mix(const float* __restrict__ Vf, const short* __restrict__ Am,
                                             float* __restrict__ Vm) {
    __shared__ unsigned int BT[2 * 64 * 33];   // pad 33: quad offsets land 2-way max (free)
    int t = threadIdx.x;
    int m  = blockIdx.x & 15;
    int ot = blockIdx.x >> 4;
    #pragma unroll
    for (int it = 0; it < 16; ++it) {
        int idx = it * 256 + t;                // 4096 = 64 i x 32 oth x 2 ri
        int oth = idx & 31, ri = (idx >> 5) & 1, i = idx >> 6;
        float sum = 0.f;
        #pragma unroll
        for (int pt = 0; pt < 4; ++pt)
            sum += Vf[((size_t)(pt * 64 + i) * 32 + m * 2 + ri) * 512 + ot * 32 + oth];
        BT[(ri * 64 + i) * 33 + oth] = bf16_split_pack(sum);
    }
    __syncthreads();
    int wv = t >> 6, lane = t & 63, quad = lane >> 4, l15 = lane & 15;
    int nt = wv & 1, mtp = wv >> 1;
    f32x4 aR[2], aI[2];
    aR[0]=(f32x4){0.f,0.f,0.f,0.f}; aR[1]=aR[0]; aI[0]=aR[0]; aI[1]=aR[0];
    #pragma unroll
    for (int kc = 0; kc < 2; ++kc) {
        short8 Brh, Brl, Bih, Bil;
        #pragma unroll
        for (int j = 0; j < 8; ++j) {
            int i = kc * 32 + quad * 8 + j;
            unsigned int br = BT[i * 33 + nt * 16 + l15];
            unsigned int bi = BT[(64 + i) * 33 + nt * 16 + l15];
            Brh[j] = (short)(br & 0xffffu); Brl[j] = (short)(br >> 16);
            Bih[j] = (short)(bi & 0xffffu); Bil[j] = (short)(bi >> 16);
        }
        #pragma unroll
        for (int mi = 0; mi < 2; ++mi) {
            int mt = mtp * 2 + mi;
            const short8* ap = (const short8*)(Am + ((size_t)(((m * 4 + mt) * 2 + kc) * 64 + lane)) * 48);
            short8 Arh = ap[0], Arl = ap[1], Aih = ap[2], Ail = ap[3], Anh = ap[4], Anl = ap[5];
            aR[mi] = MFMA16(Arh, Brh, aR[mi]);
            aR[mi] = MFMA16(Arl, Brh, aR[mi]);
            aR[mi] = MFMA16(Arh, Brl, aR[mi]);
            aR[mi] = MFMA16(Anh, Bih, aR[mi]);
            aR[mi] = MFMA16(Anl, Bih, aR[mi]);
            aR[mi] = MFMA16(Anh, Bil, aR[mi]);
            aI[mi] = MFMA16(Arh, Bih, aI[mi]);
            aI[mi] = MFMA16(Arl, Bih, aI[mi]);
            aI[mi] = MFMA16(Arh, Bil, aI[mi]);
            aI[mi] = MFMA16(Aih, Brh, aI[mi]);
            aI[mi] = MFMA16(Ail, Brh, aI[mi]);
            aI[mi] = MFMA16(Aih, Brl, aI[mi]);
        }
    }
    int oth = ot * 32 + nt * 16 + l15;
    #pragma unroll
    for (int mi = 0; mi < 2; ++mi) {
        int o = (mtp * 2 + mi) * 16 + quad * 4;
        #pragma unroll
        for (int r = 0; r < 4; ++r) {
            float2 v; v.x = aR[mi][r]; v.y = aI[mi][r];
            *(float2*)(Vm + ((size_t)(o + r) * 512 + oth) * 32 + m * 2) = v;
        }
    }
}

// ---------------------------------------------------------------------------
// Fused inverse DFT (both axes) -> s, MFMA, no LDS:
// s[p][y][w] = sum_o Gb[y][o]*VmH[p][w][o] + sum_o VmW[p][y][o]*Gb[w][o]
// G1: A=GbF(y-tile), B=VmH rows (dwordx4); G2: A=VmW rows, B=GbF(w-tile).
// grid(8 wt, 8 yt, 64 p), block 256: wave -> 16-y m-slice, loops 4 w n-tiles.
// ---------------------------------------------------------------------------
__global__ __launch_bounds__(256) void k_inv(const float* __restrict__ VmW, const float* __restrict__ VmH,
                                             const short* __restrict__ GbF, float* __restrict__ s) {
    int t = threadIdx.x;
    int wt = blockIdx.x, yt = blockIdx.y, p = blockIdx.z;
    int wv = t >> 6, lane = t & 63, quad = lane >> 4, l15 = lane & 15;
    int ys = yt * 64 + wv * 16;
    // A2 = VmW[p][ys+l15][quad*8..+8]
    const float* a2p = VmW + ((size_t)p * 512 + ys + l15) * 32 + quad * 8;
    float av[8];
    {
        float4 x0 = *(const float4*)a2p;
        float4 x1 = *(const float4*)(a2p + 4);
        av[0]=x0.x; av[1]=x0.y; av[2]=x0.z; av[3]=x0.w;
        av[4]=x1.x; av[5]=x1.y; av[6]=x1.z; av[7]=x1.w;
    }
    short8 A2h, A2l; split8(av, A2h, A2l);
    const short8* g1 = (const short8*)(GbF + (((yt * 4 + wv) * 64 + lane) << 4));
    short8 A1h = g1[0], A1l = g1[1];
    #pragma unroll
    for (int nt = 0; nt < 4; ++nt) {
        int wb = wt * 64 + nt * 16;
        const float* b1p = VmH + ((size_t)p * 512 + wb + l15) * 32 + quad * 8;
        float bv[8];
        float4 x0 = *(const float4*)b1p;
        float4 x1 = *(const float4*)(b1p + 4);
        bv[0]=x0.x; bv[1]=x0.y; bv[2]=x0.z; bv[3]=x0.w;
        bv[4]=x1.x; bv[5]=x1.y; bv[6]=x1.z; bv[7]=x1.w;
        short8 B1h, B1l; split8(bv, B1h, B1l);
        const short8* g2 = (const short8*)(GbF + (((wt * 4 + nt) * 64 + lane) << 4));
        short8 B2h = g2[0], B2l = g2[1];
        f32x4 acc = (f32x4){0.f,0.f,0.f,0.f};
        acc = MFMA16(A1h, B1h, acc);
        acc = MFMA16(A1l, B1h, acc);
        acc = MFMA16(A1h, B1l, acc);
        acc = MFMA16(A2h, B2h, acc);
        acc = MFMA16(A2l, B2h, acc);
        acc = MFMA16(A2h, B2l, acc);
        #pragma unroll
        for (int r = 0; r < 4; ++r)
            s[((size_t)p * 512 + ys + quad * 4 + r) * 512 + wb + l15] = acc[r];
    }
}

// ---------------------------------------------------------------------------
// MFMA FFN (unchanged from R2, validated): h[o][pix] += gelu(W2.gelu(W1.s+b1)+b2)
// ---------------------------------------------------------------------------
__global__ __launch_bounds__(256, 2) void k_ffn2m(const float* __restrict__ in, float* __restrict__ out,
                                                  const short* __restrict__ w1f, const float* __restrict__ b1v,
                                                  const short* __restrict__ w2f, const float* __restrict__ b2v) {
    __shared__ __align__(16) unsigned int sT[64 * 64];
    __shared__ __align__(16) unsigned int tT[64 * 64];
    int t = threadIdx.x;
    int pixBase = blockIdx.x * 64;
    int lane15 = t & 15;
    int quad   = (t >> 4) & 3;
    int wv     = t >> 6;
    int row    = wv * 16 + lane15;

    {
        int pp = t & 63;
        int cq = wv;
        for (int q = 0; q < 4; ++q) {
            int cbase = q * 16 + cq * 4;
            unsigned int pk[4];
            #pragma unroll
            for (int i = 0; i < 4; ++i) {
                float x = in[(size_t)(cbase + i) * NPIX + pixBase + pp];
                pk[i] = bf16_split_pack(x);
            }
            int cg = cbase >> 2;
            unsigned int* dst = &sT[pp * 64 + (((cg ^ (pp & 15)) << 2))];
            *(uint4*)dst = make_uint4(pk[0], pk[1], pk[2], pk[3]);
        }
    }

    short8 W1h[8], W1l[8];
    #pragma unroll
    for (int s8 = 0; s8 < 8; ++s8) {
        const short8* p = (const short8*)(w1f + (((size_t)s8 * 64 + (t & 63)) << 4));
        W1h[s8] = p[0]; W1l[s8] = p[1];
    }

    f32x4 acc[4];
    #pragma unroll
    for (int mt = 0; mt < 4; ++mt) acc[mt] = (f32x4){0.f, 0.f, 0.f, 0.f};

    __syncthreads();

    #pragma unroll
    for (int kc = 0; kc < 2; ++kc) {
        int cg0 = kc * 8 + quad * 2;
        uint4 u0 = *(const uint4*)&sT[row * 64 + ((cg0 ^ lane15) << 2)];
        uint4 u1 = *(const uint4*)&sT[row * 64 + (((cg0 + 1) ^ lane15) << 2)];
        union { unsigned int w[4]; short8 v; } bh, bl;
        bh.w[0] = (u0.x & 0xffffu) | (u0.y << 16);
        bh.w[1] = (u0.z & 0xffffu) | (u0.w << 16);
        bh.w[2] = (u1.x & 0xffffu) | (u1.y << 16);
        bh.w[3] = (u1.z & 0xffffu) | (u1.w << 16);
        bl.w[0] = (u0.x >> 16) | (u0.y & 0xffff0000u);
        bl.w[1] = (u0.z >> 16) | (u0.w & 0xffff0000u);
        bl.w[2] = (u1.x >> 16) | (u1.y & 0xffff0000u);
        bl.w[3] = (u1.z >> 16) | (u1.w & 0xffff0000u);
        #pragma unroll
        for (int mt = 0; mt < 4; ++mt) {
            int s8 = mt * 2 + kc;
            acc[mt] = MFMA16(W1h[s8], bh.v, acc[mt]);
            acc[mt] = MFMA16(W1h[s8], bl.v, acc[mt]);
            acc[mt] = MFMA16(W1l[s8], bh.v, acc[mt]);
        }
    }

    #pragma unroll
    for (int mt = 0; mt < 4; ++mt) {
        const float* bp = b1v + mt * 16 + quad * 4;
        unsigned int pk[4];
        #pragma unroll
        for (int r = 0; r < 4; ++r) {
            float g = gelu_f(acc[mt][r] + bp[r]);
            pk[r] = bf16_split_pack(g);
        }
        int cg = mt * 4 + quad;
        unsigned int* dst = &tT[row * 64 + ((cg ^ lane15) << 2)];
        *(uint4*)dst = make_uint4(pk[0], pk[1], pk[2], pk[3]);
        acc[mt] = (f32x4){0.f, 0.f, 0.f, 0.f};
    }

    short8 W2h[8], W2l[8];
    #pragma unroll
    for (int s8 = 0; s8 < 8; ++s8) {
        const short8* p = (const short8*)(w2f + (((size_t)s8 * 64 + (t & 63)) << 4));
        W2h[s8] = p[0]; W2l[s8] = p[1];
    }

    __syncthreads();

    #pragma unroll
    for (int kc = 0; kc < 2; ++kc) {
        int cg0 = kc * 8 + quad * 2;
        uint4 u0 = *(const uint4*)&tT[row * 64 + ((cg0 ^ lane15) << 2)];
        uint4 u1 = *(const uint4*)&tT[row * 64 + (((cg0 + 1) ^ lane15) << 2)];
        union { unsigned int w[4]; short8 v; } bh, bl;
        bh.w[0] = (u0.x & 0xffffu) | (u0.y << 16);
        bh.w[1] = (u0.z & 0xffffu) | (u0.w << 16);
        bh.w[2] = (u1.x & 0xffffu) | (u1.y << 16);
        bh.w[3] = (u1.z & 0xffffu) | (u1.w << 16);
        bl.w[0] = (u0.x >> 16) | (u0.y & 0xffff0000u);
        bl.w[1] = (u0.z >> 16) | (u0.w & 0xffff0000u);
        bl.w[2] = (u1.x >> 16) | (u1.y & 0xffff0000u);
        bl.w[3] = (u1.z >> 16) | (u1.w & 0xffff0000u);
        #pragma unroll
        for (int mt = 0; mt < 4; ++mt) {
            int s8 = mt * 2 + kc;
            acc[mt] = MFMA16(W2h[s8], bh.v, acc[mt]);
            acc[mt] = MFMA16(W2h[s8], bl.v, acc[mt]);
            acc[mt] = MFMA16(W2l[s8], bh.v, acc[mt]);
        }
    }

    #pragma unroll
    for (int mt = 0; mt < 4; ++mt) {
        const float* bp = b2v + mt * 16 + quad * 4;
        #pragma unroll
        for (int r = 0; r < 4; ++r) {
            int o = mt * 16 + quad * 4 + r;
            size_t ga = (size_t)o * NPIX + pixBase + row;
            out[ga] = out[ga] + gelu_f(acc[mt][r] + bp[r]);
        }
    }
}

// Decoder
__global__ __launch_bounds__(256) void k_dec(const float* __restrict__ h, const float* __restrict__ Wd,
                                             const float* __restrict__ bd, float* __restrict__ out) {
    int pix = blockIdx.x * 256 + threadIdx.x;
    float acc = bd[0];
    #pragma unroll 8
    for (int c = 0; c < 64; ++c) acc += Wd[c] * h[(size_t)c * NPIX + pix];
    out[pix] = acc;
}

extern "C" void kernel_launch(void* const* d_in, const int* in_sizes, int n_in,
                              void* d_out, int out_size, void* d_ws, size_t ws_size,
                              hipStream_t stream) {
    (void)in_sizes; (void)n_in; (void)out_size; (void)ws_size;
    const float* u   = (const float*)d_in[0];
    const float* xc  = (const float*)d_in[1];
    const float* We  = (const float*)d_in[2];
    const float* be  = (const float*)d_in[3];
    const float* W1  = (const float*)d_in[4];
    const float* b1  = (const float*)d_in[5];
    const float* W2  = (const float*)d_in[6];
    const float* b2  = (const float*)d_in[7];
    const float* Are = (const float*)d_in[8];
    const float* Aim = (const float*)d_in[9];
    const float* Wd  = (const float*)d_in[10];
    const float* bd  = (const float*)d_in[11];

    // workspace layout (float units), ~165 MB
    float* ws  = (float*)d_ws;
    float* h   = ws;                            // 64 MB
    float* s   = h   + (size_t)16777216;        // 64 MB
    float* Vf  = s   + (size_t)16777216;        // 16 MB: [4][64][32][512]
    float* VmH = Vf  + (size_t)4194304;         // 4 MB: [64][512][32]
    float* VmW = VmH + (size_t)1048576;         // 4 MB
    short* FbB = (short*)(VmW + 1048576);       // 64 KB
    short* GbF = FbB + 32768;                   // 64 KB
    short* Am  = GbF + 32768;                   // 6 MB: 65536 rec x 48 shorts
    short* Wpk = Am  + (size_t)65536 * 48;      // 128 KB

    k_bpack<<<16, 256, 0, stream>>>(FbB, GbF);
    k_afrag<<<256, 256, 0, stream>>>(Are, Aim, Am);
    k_wpack<<<16, 256, 0, stream>>>(W1, W2, Wpk);
    k_enc<<<1024, 256, 0, stream>>>(u, xc, We, be, h);

    const size_t aslab = (size_t)16 * 4 * 2 * 64 * 48;   // shorts per (l,ax)
    for (int l = 0; l < 4; ++l) {
        k_fwd_h<<<dim3(8, 64, 4), 256, 0, stream>>>(h, FbB, Vf);
        k_mix<<<256, 256, 0, stream>>>(Vf, Am + (size_t)(l * 2 + 0) * aslab, VmH);
        k_fwd_w<<<dim3(8, 64, 4), 256, 0, stream>>>(h, FbB, Vf);
        k_mix<<<256, 256, 0, stream>>>(Vf, Am + (size_t)(l * 2 + 1) * aslab, VmW);
        k_inv<<<dim3(8, 8, 64), 256, 0, stream>>>(VmW, VmH, GbF, s);
        k_ffn2m<<<4096, 256, 0, stream>>>(s, h,
                                          Wpk + (size_t)(l * 2 + 0) * 8192, b1 + (size_t)l * 64,
                                          Wpk + (size_t)(l * 2 + 1) * 8192, b2 + (size_t)l * 64);
    }
    k_dec<<<1024, 256, 0, stream>>>(h, Wd, bd, (float*)d_out);
}

// Round 5
// 622.490 us; speedup vs baseline: 1.6650x; 1.0355x over previous
//
#include <hip/hip_runtime.h>

#define NPIX (512*512)

typedef __attribute__((ext_vector_type(8))) short short8;   // 8 bf16 in 4 VGPRs
typedef __attribute__((ext_vector_type(4))) float f32x4;    // MFMA accumulator

#define MFMA16(A, B, C) __builtin_amdgcn_mfma_f32_16x16x32_bf16((A), (B), (C), 0, 0, 0)

// JAX gelu(approximate=True): x * sigmoid(2*sqrt(2/pi)*(x+0.044715x^3)); inf-safe.
__device__ __forceinline__ float gelu_f(float x) {
    return x / (1.0f + __expf(-1.5957691216057308f * (x + 0.044715f * x * x * x)));
}

// f32 -> bf16 bits (RNE)
__device__ __forceinline__ unsigned short bf16_rne(float x) {
    unsigned int b = __float_as_uint(x);
    unsigned int r = b + 0x7fffu + ((b >> 16) & 1u);
    return (unsigned short)(r >> 16);
}
__device__ __forceinline__ float bf16_tof(unsigned short h) {
    return __uint_as_float(((unsigned int)h) << 16);
}
// split x ~= hi + lo (each bf16); dropped cross term in 3-term MFMA ~2^-18 rel.
__device__ __forceinline__ unsigned int bf16_split_pack(float x) {
    unsigned short hi = bf16_rne(x);
    unsigned short lo = bf16_rne(x - bf16_tof(hi));
    return (unsigned int)hi | ((unsigned int)lo << 16);
}
__device__ __forceinline__ void split8(const float* x, short8& h, short8& l) {
    #pragma unroll
    for (int j = 0; j < 8; ++j) {
        unsigned short hi = bf16_rne(x[j]);
        h[j] = (short)hi;
        l[j] = (short)bf16_rne(x[j] - bf16_tof(hi));
    }
}

// ---------------------------------------------------------------------------
// Packed DFT basis tables (split-bf16 frag records: 16 shorts = hi[8] | lo[8]).
// FbB: record (kc<16, nt<2, lane): elem j = Fb[kc*32+quad*8+j][nt*16+l15]
// GbF: record (t<32, lane): elem j = Gb[t*16+l15][quad*8+j]
// ---------------------------------------------------------------------------
__global__ __launch_bounds__(256) void k_bpack(short* __restrict__ FbB, short* __restrict__ GbF) {
    int id = blockIdx.x * 256 + threadIdx.x;   // 4096 records
    int lane = id & 63;
    int quad = lane >> 4, l15 = lane & 15;
    short* dst;
    int n0, nstep, o0, ostep;
    float wscale = 1.0f;
    if (id < 2048) {
        int nt = (id >> 6) & 1, kc = id >> 7;
        dst = FbB + id * 16;
        n0 = kc * 32 + quad * 8; nstep = 1;
        o0 = nt * 16 + l15;      ostep = 0;
    } else {
        int id2 = id - 2048;
        dst = GbF + id2 * 16;
        int t = id2 >> 6;
        n0 = t * 16 + l15;       nstep = 0;
        o0 = quad * 8;           ostep = 1;
        wscale = 1.0f / 512.0f;
    }
    #pragma unroll
    for (int j = 0; j < 8; ++j) {
        int n = n0 + nstep * j;
        int o = o0 + ostep * j;
        int m = o >> 1, ri = o & 1;
        int k = (n * m) & 511;
        float sv, cv;
        sincosf(6.283185307179586f * (1.0f / 512.0f) * (float)k, &sv, &cv);
        float v = ri ? -sv : cv;
        if (id >= 2048) v *= (m == 0 ? 1.0f : 2.0f) * wscale;
        unsigned short hi = bf16_rne(v);
        dst[j]     = (short)hi;
        dst[8 + j] = (short)bf16_rne(v - bf16_tof(hi));
    }
}

// Pack spectral weights A into mix A-frag records of 48 shorts:
// [Ar_h8|Ar_l8|Ai_h8|Ai_l8|An_h8|An_l8] (An = -Ai).
__global__ __launch_bounds__(256) void k_afrag(const float* __restrict__ Are,
                                               const float* __restrict__ Aim,
                                               short* __restrict__ Am) {
    int id = blockIdx.x * 256 + threadIdx.x;   // 65536 records
    int lane = id & 63;
    int kc  = (id >> 6) & 1;
    int mt  = (id >> 7) & 3;
    int m   = (id >> 9) & 15;
    int lax = id >> 13;
    int l = lax >> 1, ax = lax & 1;
    int o  = mt * 16 + (lane & 15);
    int i0 = kc * 32 + ((lane >> 4) & 3) * 8;
    short* dst = Am + (size_t)id * 48;
    #pragma unroll
    for (int j = 0; j < 8; ++j) {
        size_t src = (((size_t)(l * 64 + o) * 64 + (i0 + j)) * 16 + m) * 2 + ax;
        float ar = Are[src], ai = Aim[src];
        unsigned short h;
        h = bf16_rne(ar);  dst[j]      = (short)h; dst[8 + j]  = (short)bf16_rne(ar - bf16_tof(h));
        h = bf16_rne(ai);  dst[16 + j] = (short)h; dst[24 + j] = (short)bf16_rne(ai - bf16_tof(h));
        h = bf16_rne(-ai); dst[32 + j] = (short)h; dst[40 + j] = (short)bf16_rne(-ai - bf16_tof(h));
    }
}

// Pack FFN weights into MFMA A-frag layout, split-bf16 hi/lo.
__global__ __launch_bounds__(256) void k_wpack(const float* __restrict__ W1, const float* __restrict__ W2,
                                               short* __restrict__ Wpk) {
    int tid = blockIdx.x * 256 + threadIdx.x;  // 4096 = 8 matrices * 4 mt * 2 kc * 64 lanes
    if (tid >= 4096) return;
    int lane = tid & 63;
    int kc = (tid >> 6) & 1;
    int mt = (tid >> 7) & 3;
    int wg = tid >> 9;
    int layer = wg >> 1, which = wg & 1;
    const float* Wsrc = (which ? W2 : W1) + (size_t)layer * 4096;
    int o  = mt * 16 + (lane & 15);
    int c0 = kc * 32 + ((lane >> 4) & 3) * 8;
    short* dst = Wpk + (size_t)tid * 16;
    #pragma unroll
    for (int j = 0; j < 8; ++j) {
        float x = Wsrc[o * 64 + c0 + j];
        unsigned short hi = bf16_rne(x);
        dst[j]     = (short)hi;
        dst[8 + j] = (short)bf16_rne(x - bf16_tof(hi));
    }
}

// Encoder
__global__ __launch_bounds__(256) void k_enc(const float* __restrict__ u, const float* __restrict__ xc,
                                             const float* __restrict__ We, const float* __restrict__ be,
                                             float* __restrict__ h) {
    int pix = blockIdx.x * 256 + threadIdx.x;
    float x0 = xc[pix], x1 = xc[NPIX + pix], uu = u[pix];
    #pragma unroll 8
    for (int p = 0; p < 64; ++p) {
        h[(size_t)p * NPIX + pix] = We[p * 3] * x0 + We[p * 3 + 1] * x1 + We[p * 3 + 2] * uu + be[p];
    }
}

// ---------------------------------------------------------------------------
// Forward DFT along H (y): Vf[part][p][o][w] = sum_{y in part} Fb[y][o]*h[p][y][w]
// parts=2 (K=256/block): grid(8 wtile, 64 p, 2 part), 1024 blocks (16 waves/CU).
// ---------------------------------------------------------------------------
__global__ __launch_bounds__(256) void k_fwd_h(const float* __restrict__ h, const short* __restrict__ FbB,
                                               float* __restrict__ Vf) {
    int t = threadIdx.x;
    int wt = blockIdx.x, p = blockIdx.y, part = blockIdx.z;
    int wv = t >> 6, lane = t & 63, quad = lane >> 4, l15 = lane & 15;
    int w = wt * 64 + wv * 16 + l15;
    f32x4 acc[2];
    acc[0] = (f32x4){0.f,0.f,0.f,0.f}; acc[1] = (f32x4){0.f,0.f,0.f,0.f};
    #pragma unroll
    for (int kc = 0; kc < 8; ++kc) {
        int yb = part * 256 + kc * 32 + quad * 8;
        const float* hp = h + ((size_t)p * 512 + yb) * 512 + w;
        float bv[8];
        #pragma unroll
        for (int j = 0; j < 8; ++j) bv[j] = hp[(size_t)j * 512];
        short8 Bh, Bl; split8(bv, Bh, Bl);
        int kidx = part * 8 + kc;
        #pragma unroll
        for (int mt = 0; mt < 2; ++mt) {
            const short8* ap = (const short8*)(FbB + (((kidx * 2 + mt) * 64 + lane) << 4));
            short8 Ah = ap[0], Al = ap[1];
            acc[mt] = MFMA16(Ah, Bh, acc[mt]);
            acc[mt] = MFMA16(Al, Bh, acc[mt]);
            acc[mt] = MFMA16(Ah, Bl, acc[mt]);
        }
    }
    float* vp = Vf + ((size_t)(part * 64 + p) * 32) * 512;
    #pragma unroll
    for (int mt = 0; mt < 2; ++mt)
        #pragma unroll
        for (int r = 0; r < 4; ++r)
            vp[(size_t)(mt * 16 + quad * 4 + r) * 512 + w] = acc[mt][r];
}

// Forward DFT along W: Vf[part][p][o][y], parts=2.
__global__ __launch_bounds__(256) void k_fwd_w(const float* __restrict__ h, const short* __restrict__ FbB,
                                               float* __restrict__ Vf) {
    int t = threadIdx.x;
    int yt = blockIdx.x, p = blockIdx.y, part = blockIdx.z;
    int wv = t >> 6, lane = t & 63, quad = lane >> 4, l15 = lane & 15;
    int y = yt * 64 + wv * 16 + l15;
    f32x4 acc[2];
    acc[0] = (f32x4){0.f,0.f,0.f,0.f}; acc[1] = (f32x4){0.f,0.f,0.f,0.f};
    #pragma unroll
    for (int kc = 0; kc < 8; ++kc) {
        int wb = part * 256 + kc * 32 + quad * 8;
        const float* hp = h + ((size_t)p * 512 + y) * 512 + wb;
        float bv[8];
        float4 x0 = *(const float4*)hp;
        float4 x1 = *(const float4*)(hp + 4);
        bv[0]=x0.x; bv[1]=x0.y; bv[2]=x0.z; bv[3]=x0.w;
        bv[4]=x1.x; bv[5]=x1.y; bv[6]=x1.z; bv[7]=x1.w;
        short8 Bh, Bl; split8(bv, Bh, Bl);
        int kidx = part * 8 + kc;
        #pragma unroll
        for (int mt = 0; mt < 2; ++mt) {
            const short8* ap = (const short8*)(FbB + (((kidx * 2 + mt) * 64 + lane) << 4));
            short8 Ah = ap[0], Al = ap[1];
            acc[mt] = MFMA16(Ah, Bh, acc[mt]);
            acc[mt] = MFMA16(Al, Bh, acc[mt]);
            acc[mt] = MFMA16(Ah, Bl, acc[mt]);
        }
    }
    float* vp = Vf + ((size_t)(part * 64 + p) * 32) * 512;
    #pragma unroll
    for (int mt = 0; mt < 2; ++mt)
        #pragma unroll
        for (int r = 0; r < 4; ++r)
            vp[(size_t)(mt * 16 + quad * 4 + r) * 512 + y] = acc[mt][r];
}

// ---------------------------------------------------------------------------
// Mode mixing (complex): D_re = Ar.Br + An.Bi, D_im = Ar.Bi + Ai.Br.
// grid 256 (m = bid&15, otile = bid>>4), block 256; 2 Vf parts summed in staging.
// ---------------------------------------------------------------------------
__global__ __launch_bounds__(256) void k_mix(const float* __restrict__ Vf, const short* __restrict__ Am,
                                             float* __restrict__ Vm) {
    __shared__ unsigned int BT[2 * 64 * 33];
    int t = threadIdx.x;
    int m  = blockIdx.x & 15;
    int ot = blockIdx.x >> 4;
    #pragma unroll
    for (int it = 0; it < 16; ++it) {
        int idx = it * 256 + t;                // 4096 = 64 i x 32 oth x 2 ri
        int oth = idx & 31, ri = (idx >> 5) & 1, i = idx >> 6;
        float sum = Vf[((size_t)i * 32 + m * 2 + ri) * 512 + ot * 32 + oth]
                  + Vf[((size_t)(64 + i) * 32 + m * 2 + ri) * 512 + ot * 32 + oth];
        BT[(ri * 64 + i) * 33 + oth] = bf16_split_pack(sum);
    }
    __syncthreads();
    int wv = t >> 6, lane = t & 63, quad = lane >> 4, l15 = lane & 15;
    int nt = wv & 1, mtp = wv >> 1;
    f32x4 aR[2], aI[2];
    aR[0]=(f32x4){0.f,0.f,0.f,0.f}; aR[1]=aR[0]; aI[0]=aR[0]; aI[1]=aR[0];
    #pragma unroll
    for (int kc = 0; kc < 2; ++kc) {
        short8 Brh, Brl, Bih, Bil;
        #pragma unroll
        for (int j = 0; j < 8; ++j) {
            int i = kc * 32 + quad * 8 + j;
            unsigned int br = BT[i * 33 + nt * 16 + l15];
            unsigned int bi = BT[(64 + i) * 33 + nt * 16 + l15];
            Brh[j] = (short)(br & 0xffffu); Brl[j] = (short)(br >> 16);
            Bih[j] = (short)(bi & 0xffffu); Bil[j] = (short)(bi >> 16);
        }
        #pragma unroll
        for (int mi = 0; mi < 2; ++mi) {
            int mt = mtp * 2 + mi;
            const short8* ap = (const short8*)(Am + ((size_t)(((m * 4 + mt) * 2 + kc) * 64 + lane)) * 48);
            short8 Arh = ap[0], Arl = ap[1], Aih = ap[2], Ail = ap[3], Anh = ap[4], Anl = ap[5];
            aR[mi] = MFMA16(Arh, Brh, aR[mi]);
            aR[mi] = MFMA16(Arl, Brh, aR[mi]);
            aR[mi] = MFMA16(Arh, Brl, aR[mi]);
            aR[mi] = MFMA16(Anh, Bih, aR[mi]);
            aR[mi] = MFMA16(Anl, Bih, aR[mi]);
            aR[mi] = MFMA16(Anh, Bil, aR[mi]);
            aI[mi] = MFMA16(Arh, Bih, aI[mi]);
            aI[mi] = MFMA16(Arl, Bih, aI[mi]);
            aI[mi] = MFMA16(Arh, Bil, aI[mi]);
            aI[mi] = MFMA16(Aih, Brh, aI[mi]);
            aI[mi] = MFMA16(Ail, Brh, aI[mi]);
            aI[mi] = MFMA16(Aih, Brl, aI[mi]);
        }
    }
    int oth = ot * 32 + nt * 16 + l15;
    #pragma unroll
    for (int mi = 0; mi < 2; ++mi) {
        int o = (mtp * 2 + mi) * 16 + quad * 4;
        #pragma unroll
        for (int r = 0; r < 4; ++r) {
            float2 v; v.x = aR[mi][r]; v.y = aI[mi][r];
            *(float2*)(Vm + ((size_t)(o + r) * 512 + oth) * 32 + m * 2) = v;
        }
    }
}

// ---------------------------------------------------------------------------
// Fused inverse DFT (both axes) -> s (SPLIT-PACKED u32: hi-bf16 | lo-bf16<<16).
// s[p][y][w] = sum_o Gb[y][o]*VmH[p][w][o] + sum_o VmW[p][y][o]*Gb[w][o]
// grid(8 wt, 8 yt, 64 p), block 256.
// ---------------------------------------------------------------------------
__global__ __launch_bounds__(256) void k_inv(const float* __restrict__ VmW, const float* __restrict__ VmH,
                                             const short* __restrict__ GbF, unsigned int* __restrict__ s) {
    int t = threadIdx.x;
    int wt = blockIdx.x, yt = blockIdx.y, p = blockIdx.z;
    int wv = t >> 6, lane = t & 63, quad = lane >> 4, l15 = lane & 15;
    int ys = yt * 64 + wv * 16;
    const float* a2p = VmW + ((size_t)p * 512 + ys + l15) * 32 + quad * 8;
    float av[8];
    {
        float4 x0 = *(const float4*)a2p;
        float4 x1 = *(const float4*)(a2p + 4);
        av[0]=x0.x; av[1]=x0.y; av[2]=x0.z; av[3]=x0.w;
        av[4]=x1.x; av[5]=x1.y; av[6]=x1.z; av[7]=x1.w;
    }
    short8 A2h, A2l; split8(av, A2h, A2l);
    const short8* g1 = (const short8*)(GbF + (((yt * 4 + wv) * 64 + lane) << 4));
    short8 A1h = g1[0], A1l = g1[1];
    #pragma unroll
    for (int nt = 0; nt < 4; ++nt) {
        int wb = wt * 64 + nt * 16;
        const float* b1p = VmH + ((size_t)p * 512 + wb + l15) * 32 + quad * 8;
        float bv[8];
        float4 x0 = *(const float4*)b1p;
        float4 x1 = *(const float4*)(b1p + 4);
        bv[0]=x0.x; bv[1]=x0.y; bv[2]=x0.z; bv[3]=x0.w;
        bv[4]=x1.x; bv[5]=x1.y; bv[6]=x1.z; bv[7]=x1.w;
        short8 B1h, B1l; split8(bv, B1h, B1l);
        const short8* g2 = (const short8*)(GbF + (((wt * 4 + nt) * 64 + lane) << 4));
        short8 B2h = g2[0], B2l = g2[1];
        f32x4 acc = (f32x4){0.f,0.f,0.f,0.f};
        acc = MFMA16(A1h, B1h, acc);
        acc = MFMA16(A1l, B1h, acc);
        acc = MFMA16(A1h, B1l, acc);
        acc = MFMA16(A2h, B2h, acc);
        acc = MFMA16(A2l, B2h, acc);
        acc = MFMA16(A2h, B2l, acc);
        #pragma unroll
        for (int r = 0; r < 4; ++r)
            s[((size_t)p * 512 + ys + quad * 4 + r) * 512 + wb + l15] = bf16_split_pack(acc[r]);
    }
}

// ---------------------------------------------------------------------------
// MFMA FFN: h[o][pix] += gelu(W2.gelu(W1.s+b1)+b2). s arrives pre-split-packed.
// Epilogue2 transposes through stride-68 f32 LDS -> float4 h RMW.
// ---------------------------------------------------------------------------
__global__ __launch_bounds__(256, 2) void k_ffn2m(const unsigned int* __restrict__ in, float* __restrict__ out,
                                                  const short* __restrict__ w1f, const float* __restrict__ b1v,
                                                  const short* __restrict__ w2f, const float* __restrict__ b2v) {
    __shared__ __align__(16) unsigned int sT[64 * 64];
    __shared__ __align__(16) unsigned int tT[64 * 64];
    __shared__ __align__(16) float oT[64 * 68];   // stride 68: aligned float4, quads spread banks
    int t = threadIdx.x;
    int pixBase = blockIdx.x * 64;
    int lane15 = t & 15;
    int quad   = (t >> 4) & 3;
    int wv     = t >> 6;
    int row    = wv * 16 + lane15;

    // ---- stage s tile (already split-packed): u32 loads -> swizzled LDS ----
    {
        int pp = t & 63;
        int cq = wv;
        for (int q = 0; q < 4; ++q) {
            int cbase = q * 16 + cq * 4;
            unsigned int pk[4];
            #pragma unroll
            for (int i = 0; i < 4; ++i)
                pk[i] = in[(size_t)(cbase + i) * NPIX + pixBase + pp];
            int cg = cbase >> 2;
            unsigned int* dst = &sT[pp * 64 + (((cg ^ (pp & 15)) << 2))];
            *(uint4*)dst = make_uint4(pk[0], pk[1], pk[2], pk[3]);
        }
    }

    short8 W1h[8], W1l[8];
    #pragma unroll
    for (int s8 = 0; s8 < 8; ++s8) {
        const short8* p = (const short8*)(w1f + (((size_t)s8 * 64 + (t & 63)) << 4));
        W1h[s8] = p[0]; W1l[s8] = p[1];
    }

    f32x4 acc[4];
    #pragma unroll
    for (int mt = 0; mt < 4; ++mt) acc[mt] = (f32x4){0.f, 0.f, 0.f, 0.f};

    __syncthreads();

    // ---- GEMM1 ----
    #pragma unroll
    for (int kc = 0; kc < 2; ++kc) {
        int cg0 = kc * 8 + quad * 2;
        uint4 u0 = *(const uint4*)&sT[row * 64 + ((cg0 ^ lane15) << 2)];
        uint4 u1 = *(const uint4*)&sT[row * 64 + (((cg0 + 1) ^ lane15) << 2)];
        union { unsigned int w[4]; short8 v; } bh, bl;
        bh.w[0] = (u0.x & 0xffffu) | (u0.y << 16);
        bh.w[1] = (u0.z & 0xffffu) | (u0.w << 16);
        bh.w[2] = (u1.x & 0xffffu) | (u1.y << 16);
        bh.w[3] = (u1.z & 0xffffu) | (u1.w << 16);
        bl.w[0] = (u0.x >> 16) | (u0.y & 0xffff0000u);
        bl.w[1] = (u0.z >> 16) | (u0.w & 0xffff0000u);
        bl.w[2] = (u1.x >> 16) | (u1.y & 0xffff0000u);
        bl.w[3] = (u1.z >> 16) | (u1.w & 0xffff0000u);
        #pragma unroll
        for (int mt = 0; mt < 4; ++mt) {
            int s8 = mt * 2 + kc;
            acc[mt] = MFMA16(W1h[s8], bh.v, acc[mt]);
            acc[mt] = MFMA16(W1h[s8], bl.v, acc[mt]);
            acc[mt] = MFMA16(W1l[s8], bh.v, acc[mt]);
        }
    }

    // ---- epilogue1: gelu, split, write tT ----
    #pragma unroll
    for (int mt = 0; mt < 4; ++mt) {
        const float* bp = b1v + mt * 16 + quad * 4;
        unsigned int pk[4];
        #pragma unroll
        for (int r = 0; r < 4; ++r) {
            float g = gelu_f(acc[mt][r] + bp[r]);
            pk[r] = bf16_split_pack(g);
        }
        int cg = mt * 4 + quad;
        unsigned int* dst = &tT[row * 64 + ((cg ^ lane15) << 2)];
        *(uint4*)dst = make_uint4(pk[0], pk[1], pk[2], pk[3]);
        acc[mt] = (f32x4){0.f, 0.f, 0.f, 0.f};
    }

    short8 W2h[8], W2l[8];
    #pragma unroll
    for (int s8 = 0; s8 < 8; ++s8) {
        const short8* p = (const short8*)(w2f + (((size_t)s8 * 64 + (t & 63)) << 4));
        W2h[s8] = p[0]; W2l[s8] = p[1];
    }

    __syncthreads();

    // ---- GEMM2 ----
    #pragma unroll
    for (int kc = 0; kc < 2; ++kc) {
        int cg0 = kc * 8 + quad * 2;
        uint4 u0 = *(const uint4*)&tT[row * 64 + ((cg0 ^ lane15) << 2)];
        uint4 u1 = *(const uint4*)&tT[row * 64 + (((cg0 + 1) ^ lane15) << 2)];
        union { unsigned int w[4]; short8 v; } bh, bl;
        bh.w[0] = (u0.x & 0xffffu) | (u0.y << 16);
        bh.w[1] = (u0.z & 0xffffu) | (u0.w << 16);
        bh.w[2] = (u1.x & 0xffffu) | (u1.y << 16);
        bh.w[3] = (u1.z & 0xffffu) | (u1.w << 16);
        bl.w[0] = (u0.x >> 16) | (u0.y & 0xffff0000u);
        bl.w[1] = (u0.z >> 16) | (u0.w & 0xffff0000u);
        bl.w[2] = (u1.x >> 16) | (u1.y & 0xffff0000u);
        bl.w[3] = (u1.z >> 16) | (u1.w & 0xffff0000u);
        #pragma unroll
        for (int mt = 0; mt < 4; ++mt) {
            int s8 = mt * 2 + kc;
            acc[mt] = MFMA16(W2h[s8], bh.v, acc[mt]);
            acc[mt] = MFMA16(W2h[s8], bl.v, acc[mt]);
            acc[mt] = MFMA16(W2l[s8], bh.v, acc[mt]);
        }
    }

    // ---- epilogue2: gelu -> oT (f32, stride 68), then float4 h RMW ----
    #pragma unroll
    for (int mt = 0; mt < 4; ++mt) {
        const float* bp = b2v + mt * 16 + quad * 4;
        #pragma unroll
        for (int r = 0; r < 4; ++r) {
            int o = mt * 16 + quad * 4 + r;
            oT[o * 68 + row] = gelu_f(acc[mt][r] + bp[r]);
        }
    }
    __syncthreads();
    {
        int pix0 = (t & 15) * 4;
        int c0 = (t >> 4) * 4;                 // wave wv covers c = wv*16..+16
        #pragma unroll
        for (int i = 0; i < 4; ++i) {
            int c = c0 + i;
            float4 gv = *(const float4*)&oT[c * 68 + pix0];
            float* op = out + (size_t)c * NPIX + pixBase + pix0;
            float4 cur = *(const float4*)op;
            cur.x += gv.x; cur.y += gv.y; cur.z += gv.z; cur.w += gv.w;
            *(float4*)op = cur;
        }
    }
}

// Decoder
__global__ __launch_bounds__(256) void k_dec(const float* __restrict__ h, const float* __restrict__ Wd,
                                             const float* __restrict__ bd, float* __restrict__ out) {
    int pix = blockIdx.x * 256 + threadIdx.x;
    float acc = bd[0];
    #pragma unroll 8
    for (int c = 0; c < 64; ++c) acc += Wd[c] * h[(size_t)c * NPIX + pix];
    out[pix] = acc;
}

extern "C" void kernel_launch(void* const* d_in, const int* in_sizes, int n_in,
                              void* d_out, int out_size, void* d_ws, size_t ws_size,
                              hipStream_t stream) {
    (void)in_sizes; (void)n_in; (void)out_size; (void)ws_size;
    const float* u   = (const float*)d_in[0];
    const float* xc  = (const float*)d_in[1];
    const float* We  = (const float*)d_in[2];
    const float* be  = (const float*)d_in[3];
    const float* W1  = (const float*)d_in[4];
    const float* b1  = (const float*)d_in[5];
    const float* W2  = (const float*)d_in[6];
    const float* b2  = (const float*)d_in[7];
    const float* Are = (const float*)d_in[8];
    const float* Aim = (const float*)d_in[9];
    const float* Wd  = (const float*)d_in[10];
    const float* bd  = (const float*)d_in[11];

    // workspace layout (float units), ~165 MB
    float* ws  = (float*)d_ws;
    float* h   = ws;                            // 64 MB
    unsigned int* s = (unsigned int*)(h + (size_t)16777216);  // 64 MB (split-packed)
    float* Vf  = (float*)(s + (size_t)16777216); // 8 MB used: [2][64][32][512] (16 MB reserved)
    float* VmH = Vf  + (size_t)4194304;         // 4 MB: [64][512][32]
    float* VmW = VmH + (size_t)1048576;         // 4 MB
    short* FbB = (short*)(VmW + 1048576);       // 64 KB
    short* GbF = FbB + 32768;                   // 64 KB
    short* Am  = GbF + 32768;                   // 6 MB: 65536 rec x 48 shorts
    short* Wpk = Am  + (size_t)65536 * 48;      // 128 KB

    k_bpack<<<16, 256, 0, stream>>>(FbB, GbF);
    k_afrag<<<256, 256, 0, stream>>>(Are, Aim, Am);
    k_wpack<<<16, 256, 0, stream>>>(W1, W2, Wpk);
    k_enc<<<1024, 256, 0, stream>>>(u, xc, We, be, h);

    const size_t aslab = (size_t)16 * 4 * 2 * 64 * 48;   // shorts per (l,ax)
    for (int l = 0; l < 4; ++l) {
        k_fwd_h<<<dim3(8, 64, 2), 256, 0, stream>>>(h, FbB, Vf);
        k_mix<<<256, 256, 0, stream>>>(Vf, Am + (size_t)(l * 2 + 0) * aslab, VmH);
        k_fwd_w<<<dim3(8, 64, 2), 256, 0, stream>>>(h, FbB, Vf);
        k_mix<<<256, 256, 0, stream>>>(Vf, Am + (size_t)(l * 2 + 1) * aslab, VmW);
        k_inv<<<dim3(8, 8, 64), 256, 0, stream>>>(VmW, VmH, GbF, s);
        k_ffn2m<<<4096, 256, 0, stream>>>(s, h,
                                          Wpk + (size_t)(l * 2 + 0) * 8192, b1 + (size_t)l * 64,
                                          Wpk + (size_t)(l * 2 + 1) * 8192, b2 + (size_t)l * 64);
    }
    k_dec<<<1024, 256, 0, stream>>>(h, Wd, bd, (float*)d_out);
}

// Round 6
// 617.070 us; speedup vs baseline: 1.6796x; 1.0088x over previous
//
#include <hip/hip_runtime.h>

#define NPIX (512*512)

typedef __attribute__((ext_vector_type(8))) short short8;   // 8 bf16 in 4 VGPRs
typedef __attribute__((ext_vector_type(4))) float f32x4;    // MFMA accumulator

#define MFMA16(A, B, C) __builtin_amdgcn_mfma_f32_16x16x32_bf16((A), (B), (C), 0, 0, 0)

// JAX gelu(approximate=True): x * sigmoid(2*sqrt(2/pi)*(x+0.044715x^3)); inf-safe.
__device__ __forceinline__ float gelu_f(float x) {
    return x / (1.0f + __expf(-1.5957691216057308f * (x + 0.044715f * x * x * x)));
}

// f32 -> bf16 bits (RNE)
__device__ __forceinline__ unsigned short bf16_rne(float x) {
    unsigned int b = __float_as_uint(x);
    unsigned int r = b + 0x7fffu + ((b >> 16) & 1u);
    return (unsigned short)(r >> 16);
}
__device__ __forceinline__ float bf16_tof(unsigned short h) {
    return __uint_as_float(((unsigned int)h) << 16);
}
// split x ~= hi + lo (each bf16); dropped cross term in 3-term MFMA ~2^-18 rel.
__device__ __forceinline__ unsigned int bf16_split_pack(float x) {
    unsigned short hi = bf16_rne(x);
    unsigned short lo = bf16_rne(x - bf16_tof(hi));
    return (unsigned int)hi | ((unsigned int)lo << 16);
}
__device__ __forceinline__ void split8(const float* x, short8& h, short8& l) {
    #pragma unroll
    for (int j = 0; j < 8; ++j) {
        unsigned short hi = bf16_rne(x[j]);
        h[j] = (short)hi;
        l[j] = (short)bf16_rne(x[j] - bf16_tof(hi));
    }
}

// ---------------------------------------------------------------------------
// Packed DFT basis tables (split-bf16 frag records: 16 shorts = hi[8] | lo[8]).
// FbB: record (kc<16, nt<2, lane): elem j = Fb[kc*32+quad*8+j][nt*16+l15]
// GbF: record (t<32, lane): elem j = Gb[t*16+l15][quad*8+j]
// ---------------------------------------------------------------------------
__global__ __launch_bounds__(256) void k_bpack(short* __restrict__ FbB, short* __restrict__ GbF) {
    int id = blockIdx.x * 256 + threadIdx.x;   // 4096 records
    int lane = id & 63;
    int quad = lane >> 4, l15 = lane & 15;
    short* dst;
    int n0, nstep, o0, ostep;
    float wscale = 1.0f;
    if (id < 2048) {
        int nt = (id >> 6) & 1, kc = id >> 7;
        dst = FbB + id * 16;
        n0 = kc * 32 + quad * 8; nstep = 1;
        o0 = nt * 16 + l15;      ostep = 0;
    } else {
        int id2 = id - 2048;
        dst = GbF + id2 * 16;
        int t = id2 >> 6;
        n0 = t * 16 + l15;       nstep = 0;
        o0 = quad * 8;           ostep = 1;
        wscale = 1.0f / 512.0f;
    }
    #pragma unroll
    for (int j = 0; j < 8; ++j) {
        int n = n0 + nstep * j;
        int o = o0 + ostep * j;
        int m = o >> 1, ri = o & 1;
        int k = (n * m) & 511;
        float sv, cv;
        sincosf(6.283185307179586f * (1.0f / 512.0f) * (float)k, &sv, &cv);
        float v = ri ? -sv : cv;
        if (id >= 2048) v *= (m == 0 ? 1.0f : 2.0f) * wscale;
        unsigned short hi = bf16_rne(v);
        dst[j]     = (short)hi;
        dst[8 + j] = (short)bf16_rne(v - bf16_tof(hi));
    }
}

// Pack spectral weights A into mix A-frag records of 48 shorts:
// [Ar_h8|Ar_l8|Ai_h8|Ai_l8|An_h8|An_l8] (An = -Ai).
__global__ __launch_bounds__(256) void k_afrag(const float* __restrict__ Are,
                                               const float* __restrict__ Aim,
                                               short* __restrict__ Am) {
    int id = blockIdx.x * 256 + threadIdx.x;   // 65536 records
    int lane = id & 63;
    int kc  = (id >> 6) & 1;
    int mt  = (id >> 7) & 3;
    int m   = (id >> 9) & 15;
    int lax = id >> 13;
    int l = lax >> 1, ax = lax & 1;
    int o  = mt * 16 + (lane & 15);
    int i0 = kc * 32 + ((lane >> 4) & 3) * 8;
    short* dst = Am + (size_t)id * 48;
    #pragma unroll
    for (int j = 0; j < 8; ++j) {
        size_t src = (((size_t)(l * 64 + o) * 64 + (i0 + j)) * 16 + m) * 2 + ax;
        float ar = Are[src], ai = Aim[src];
        unsigned short h;
        h = bf16_rne(ar);  dst[j]      = (short)h; dst[8 + j]  = (short)bf16_rne(ar - bf16_tof(h));
        h = bf16_rne(ai);  dst[16 + j] = (short)h; dst[24 + j] = (short)bf16_rne(ai - bf16_tof(h));
        h = bf16_rne(-ai); dst[32 + j] = (short)h; dst[40 + j] = (short)bf16_rne(-ai - bf16_tof(h));
    }
}

// Pack FFN weights into MFMA A-frag layout, split-bf16 hi/lo.
__global__ __launch_bounds__(256) void k_wpack(const float* __restrict__ W1, const float* __restrict__ W2,
                                               short* __restrict__ Wpk) {
    int tid = blockIdx.x * 256 + threadIdx.x;  // 4096 = 8 matrices * 4 mt * 2 kc * 64 lanes
    if (tid >= 4096) return;
    int lane = tid & 63;
    int kc = (tid >> 6) & 1;
    int mt = (tid >> 7) & 3;
    int wg = tid >> 9;
    int layer = wg >> 1, which = wg & 1;
    const float* Wsrc = (which ? W2 : W1) + (size_t)layer * 4096;
    int o  = mt * 16 + (lane & 15);
    int c0 = kc * 32 + ((lane >> 4) & 3) * 8;
    short* dst = Wpk + (size_t)tid * 16;
    #pragma unroll
    for (int j = 0; j < 8; ++j) {
        float x = Wsrc[o * 64 + c0 + j];
        unsigned short hi = bf16_rne(x);
        dst[j]     = (short)hi;
        dst[8 + j] = (short)bf16_rne(x - bf16_tof(hi));
    }
}

// Encoder
__global__ __launch_bounds__(256) void k_enc(const float* __restrict__ u, const float* __restrict__ xc,
                                             const float* __restrict__ We, const float* __restrict__ be,
                                             float* __restrict__ h) {
    int pix = blockIdx.x * 256 + threadIdx.x;
    float x0 = xc[pix], x1 = xc[NPIX + pix], uu = u[pix];
    #pragma unroll 8
    for (int p = 0; p < 64; ++p) {
        h[(size_t)p * NPIX + pix] = We[p * 3] * x0 + We[p * 3 + 1] * x1 + We[p * 3 + 2] * uu + be[p];
    }
}

// ---------------------------------------------------------------------------
// Forward DFT along H (y): Vf[part][p][o][w] = sum_{y in part} Fb[y][o]*h[p][y][w]
// parts=2 (K=256/block): grid(8 wtile, 64 p, 2 part).
// ---------------------------------------------------------------------------
__global__ __launch_bounds__(256) void k_fwd_h(const float* __restrict__ h, const short* __restrict__ FbB,
                                               float* __restrict__ Vf) {
    int t = threadIdx.x;
    int wt = blockIdx.x, p = blockIdx.y, part = blockIdx.z;
    int wv = t >> 6, lane = t & 63, quad = lane >> 4, l15 = lane & 15;
    int w = wt * 64 + wv * 16 + l15;
    f32x4 acc[2];
    acc[0] = (f32x4){0.f,0.f,0.f,0.f}; acc[1] = (f32x4){0.f,0.f,0.f,0.f};
    #pragma unroll
    for (int kc = 0; kc < 8; ++kc) {
        int yb = part * 256 + kc * 32 + quad * 8;
        const float* hp = h + ((size_t)p * 512 + yb) * 512 + w;
        float bv[8];
        #pragma unroll
        for (int j = 0; j < 8; ++j) bv[j] = hp[(size_t)j * 512];
        short8 Bh, Bl; split8(bv, Bh, Bl);
        int kidx = part * 8 + kc;
        #pragma unroll
        for (int mt = 0; mt < 2; ++mt) {
            const short8* ap = (const short8*)(FbB + (((kidx * 2 + mt) * 64 + lane) << 4));
            short8 Ah = ap[0], Al = ap[1];
            acc[mt] = MFMA16(Ah, Bh, acc[mt]);
            acc[mt] = MFMA16(Al, Bh, acc[mt]);
            acc[mt] = MFMA16(Ah, Bl, acc[mt]);
        }
    }
    float* vp = Vf + ((size_t)(part * 64 + p) * 32) * 512;
    #pragma unroll
    for (int mt = 0; mt < 2; ++mt)
        #pragma unroll
        for (int r = 0; r < 4; ++r)
            vp[(size_t)(mt * 16 + quad * 4 + r) * 512 + w] = acc[mt][r];
}

// Forward DFT along W: Vf[part][p][o][y], parts=2.
__global__ __launch_bounds__(256) void k_fwd_w(const float* __restrict__ h, const short* __restrict__ FbB,
                                               float* __restrict__ Vf) {
    int t = threadIdx.x;
    int yt = blockIdx.x, p = blockIdx.y, part = blockIdx.z;
    int wv = t >> 6, lane = t & 63, quad = lane >> 4, l15 = lane & 15;
    int y = yt * 64 + wv * 16 + l15;
    f32x4 acc[2];
    acc[0] = (f32x4){0.f,0.f,0.f,0.f}; acc[1] = (f32x4){0.f,0.f,0.f,0.f};
    #pragma unroll
    for (int kc = 0; kc < 8; ++kc) {
        int wb = part * 256 + kc * 32 + quad * 8;
        const float* hp = h + ((size_t)p * 512 + y) * 512 + wb;
        float bv[8];
        float4 x0 = *(const float4*)hp;
        float4 x1 = *(const float4*)(hp + 4);
        bv[0]=x0.x; bv[1]=x0.y; bv[2]=x0.z; bv[3]=x0.w;
        bv[4]=x1.x; bv[5]=x1.y; bv[6]=x1.z; bv[7]=x1.w;
        short8 Bh, Bl; split8(bv, Bh, Bl);
        int kidx = part * 8 + kc;
        #pragma unroll
        for (int mt = 0; mt < 2; ++mt) {
            const short8* ap = (const short8*)(FbB + (((kidx * 2 + mt) * 64 + lane) << 4));
            short8 Ah = ap[0], Al = ap[1];
            acc[mt] = MFMA16(Ah, Bh, acc[mt]);
            acc[mt] = MFMA16(Al, Bh, acc[mt]);
            acc[mt] = MFMA16(Ah, Bl, acc[mt]);
        }
    }
    float* vp = Vf + ((size_t)(part * 64 + p) * 32) * 512;
    #pragma unroll
    for (int mt = 0; mt < 2; ++mt)
        #pragma unroll
        for (int r = 0; r < 4; ++r)
            vp[(size_t)(mt * 16 + quad * 4 + r) * 512 + y] = acc[mt][r];
}

// ---------------------------------------------------------------------------
// Mode mixing (complex): D_re = Ar.Br + An.Bi, D_im = Ar.Bi + Ai.Br.
// grid 256 (m = bid&15, otile = bid>>4), block 256; 2 Vf parts summed in staging.
// ---------------------------------------------------------------------------
__global__ __launch_bounds__(256) void k_mix(const float* __restrict__ Vf, const short* __restrict__ Am,
                                             float* __restrict__ Vm) {
    __shared__ unsigned int BT[2 * 64 * 33];
    int t = threadIdx.x;
    int m  = blockIdx.x & 15;
    int ot = blockIdx.x >> 4;
    #pragma unroll
    for (int it = 0; it < 16; ++it) {
        int idx = it * 256 + t;                // 4096 = 64 i x 32 oth x 2 ri
        int oth = idx & 31, ri = (idx >> 5) & 1, i = idx >> 6;
        float sum = Vf[((size_t)i * 32 + m * 2 + ri) * 512 + ot * 32 + oth]
                  + Vf[((size_t)(64 + i) * 32 + m * 2 + ri) * 512 + ot * 32 + oth];
        BT[(ri * 64 + i) * 33 + oth] = bf16_split_pack(sum);
    }
    __syncthreads();
    int wv = t >> 6, lane = t & 63, quad = lane >> 4, l15 = lane & 15;
    int nt = wv & 1, mtp = wv >> 1;
    f32x4 aR[2], aI[2];
    aR[0]=(f32x4){0.f,0.f,0.f,0.f}; aR[1]=aR[0]; aI[0]=aR[0]; aI[1]=aR[0];
    #pragma unroll
    for (int kc = 0; kc < 2; ++kc) {
        short8 Brh, Brl, Bih, Bil;
        #pragma unroll
        for (int j = 0; j < 8; ++j) {
            int i = kc * 32 + quad * 8 + j;
            unsigned int br = BT[i * 33 + nt * 16 + l15];
            unsigned int bi = BT[(64 + i) * 33 + nt * 16 + l15];
            Brh[j] = (short)(br & 0xffffu); Brl[j] = (short)(br >> 16);
            Bih[j] = (short)(bi & 0xffffu); Bil[j] = (short)(bi >> 16);
        }
        #pragma unroll
        for (int mi = 0; mi < 2; ++mi) {
            int mt = mtp * 2 + mi;
            const short8* ap = (const short8*)(Am + ((size_t)(((m * 4 + mt) * 2 + kc) * 64 + lane)) * 48);
            short8 Arh = ap[0], Arl = ap[1], Aih = ap[2], Ail = ap[3], Anh = ap[4], Anl = ap[5];
            aR[mi] = MFMA16(Arh, Brh, aR[mi]);
            aR[mi] = MFMA16(Arl, Brh, aR[mi]);
            aR[mi] = MFMA16(Arh, Brl, aR[mi]);
            aR[mi] = MFMA16(Anh, Bih, aR[mi]);
            aR[mi] = MFMA16(Anl, Bih, aR[mi]);
            aR[mi] = MFMA16(Anh, Bil, aR[mi]);
            aI[mi] = MFMA16(Arh, Bih, aI[mi]);
            aI[mi] = MFMA16(Arl, Bih, aI[mi]);
            aI[mi] = MFMA16(Arh, Bil, aI[mi]);
            aI[mi] = MFMA16(Aih, Brh, aI[mi]);
            aI[mi] = MFMA16(Ail, Brh, aI[mi]);
            aI[mi] = MFMA16(Aih, Brl, aI[mi]);
        }
    }
    int oth = ot * 32 + nt * 16 + l15;
    #pragma unroll
    for (int mi = 0; mi < 2; ++mi) {
        int o = (mtp * 2 + mi) * 16 + quad * 4;
        #pragma unroll
        for (int r = 0; r < 4; ++r) {
            float2 v; v.x = aR[mi][r]; v.y = aI[mi][r];
            *(float2*)(Vm + ((size_t)(o + r) * 512 + oth) * 32 + m * 2) = v;
        }
    }
}

// ---------------------------------------------------------------------------
// Fused inverse DFT (both axes) -> s (SPLIT-PACKED u32: hi-bf16 | lo-bf16<<16).
// grid(8 wt, 8 yt, 64 p), block 256.
// ---------------------------------------------------------------------------
__global__ __launch_bounds__(256) void k_inv(const float* __restrict__ VmW, const float* __restrict__ VmH,
                                             const short* __restrict__ GbF, unsigned int* __restrict__ s) {
    int t = threadIdx.x;
    int wt = blockIdx.x, yt = blockIdx.y, p = blockIdx.z;
    int wv = t >> 6, lane = t & 63, quad = lane >> 4, l15 = lane & 15;
    int ys = yt * 64 + wv * 16;
    const float* a2p = VmW + ((size_t)p * 512 + ys + l15) * 32 + quad * 8;
    float av[8];
    {
        float4 x0 = *(const float4*)a2p;
        float4 x1 = *(const float4*)(a2p + 4);
        av[0]=x0.x; av[1]=x0.y; av[2]=x0.z; av[3]=x0.w;
        av[4]=x1.x; av[5]=x1.y; av[6]=x1.z; av[7]=x1.w;
    }
    short8 A2h, A2l; split8(av, A2h, A2l);
    const short8* g1 = (const short8*)(GbF + (((yt * 4 + wv) * 64 + lane) << 4));
    short8 A1h = g1[0], A1l = g1[1];
    #pragma unroll
    for (int nt = 0; nt < 4; ++nt) {
        int wb = wt * 64 + nt * 16;
        const float* b1p = VmH + ((size_t)p * 512 + wb + l15) * 32 + quad * 8;
        float bv[8];
        float4 x0 = *(const float4*)b1p;
        float4 x1 = *(const float4*)(b1p + 4);
        bv[0]=x0.x; bv[1]=x0.y; bv[2]=x0.z; bv[3]=x0.w;
        bv[4]=x1.x; bv[5]=x1.y; bv[6]=x1.z; bv[7]=x1.w;
        short8 B1h, B1l; split8(bv, B1h, B1l);
        const short8* g2 = (const short8*)(GbF + (((wt * 4 + nt) * 64 + lane) << 4));
        short8 B2h = g2[0], B2l = g2[1];
        f32x4 acc = (f32x4){0.f,0.f,0.f,0.f};
        acc = MFMA16(A1h, B1h, acc);
        acc = MFMA16(A1l, B1h, acc);
        acc = MFMA16(A1h, B1l, acc);
        acc = MFMA16(A2h, B2h, acc);
        acc = MFMA16(A2l, B2h, acc);
        acc = MFMA16(A2h, B2l, acc);
        #pragma unroll
        for (int r = 0; r < 4; ++r)
            s[((size_t)p * 512 + ys + quad * 4 + r) * 512 + wb + l15] = bf16_split_pack(acc[r]);
    }
}

// ---------------------------------------------------------------------------
// MFMA FFN: h[o][pix] += gelu(W2.gelu(W1.s+b1)+b2). s arrives pre-split-packed.
// oT aliases sT (union): sT dead after GEMM1; the pre-GEMM2 __syncthreads
// fences all waves past it. LDS 33792 B -> 4 blocks/CU (135 KB < 160 KB).
// ---------------------------------------------------------------------------
union FfnSmem {
    unsigned int sT[64 * 64];   // 16384 B, staging + GEMM1 B-operand
    float oT[64 * 68];          // 17408 B, epilogue2 transpose tile
};

__global__ __launch_bounds__(256, 4) void k_ffn2m(const unsigned int* __restrict__ in, float* __restrict__ out,
                                                  const short* __restrict__ w1f, const float* __restrict__ b1v,
                                                  const short* __restrict__ w2f, const float* __restrict__ b2v) {
    __shared__ __align__(16) FfnSmem u;
    __shared__ __align__(16) unsigned int tT[64 * 64];
    int t = threadIdx.x;
    int pixBase = blockIdx.x * 64;
    int lane15 = t & 15;
    int quad   = (t >> 4) & 3;
    int wv     = t >> 6;
    int row    = wv * 16 + lane15;

    // ---- stage s tile (already split-packed): u32 loads -> swizzled LDS ----
    {
        int pp = t & 63;
        int cq = wv;
        for (int q = 0; q < 4; ++q) {
            int cbase = q * 16 + cq * 4;
            unsigned int pk[4];
            #pragma unroll
            for (int i = 0; i < 4; ++i)
                pk[i] = in[(size_t)(cbase + i) * NPIX + pixBase + pp];
            int cg = cbase >> 2;
            unsigned int* dst = &u.sT[pp * 64 + (((cg ^ (pp & 15)) << 2))];
            *(uint4*)dst = make_uint4(pk[0], pk[1], pk[2], pk[3]);
        }
    }

    short8 W1h[8], W1l[8];
    #pragma unroll
    for (int s8 = 0; s8 < 8; ++s8) {
        const short8* p = (const short8*)(w1f + (((size_t)s8 * 64 + (t & 63)) << 4));
        W1h[s8] = p[0]; W1l[s8] = p[1];
    }

    f32x4 acc[4];
    #pragma unroll
    for (int mt = 0; mt < 4; ++mt) acc[mt] = (f32x4){0.f, 0.f, 0.f, 0.f};

    __syncthreads();

    // ---- GEMM1 ----
    #pragma unroll
    for (int kc = 0; kc < 2; ++kc) {
        int cg0 = kc * 8 + quad * 2;
        uint4 u0 = *(const uint4*)&u.sT[row * 64 + ((cg0 ^ lane15) << 2)];
        uint4 u1 = *(const uint4*)&u.sT[row * 64 + (((cg0 + 1) ^ lane15) << 2)];
        union { unsigned int w[4]; short8 v; } bh, bl;
        bh.w[0] = (u0.x & 0xffffu) | (u0.y << 16);
        bh.w[1] = (u0.z & 0xffffu) | (u0.w << 16);
        bh.w[2] = (u1.x & 0xffffu) | (u1.y << 16);
        bh.w[3] = (u1.z & 0xffffu) | (u1.w << 16);
        bl.w[0] = (u0.x >> 16) | (u0.y & 0xffff0000u);
        bl.w[1] = (u0.z >> 16) | (u0.w & 0xffff0000u);
        bl.w[2] = (u1.x >> 16) | (u1.y & 0xffff0000u);
        bl.w[3] = (u1.z >> 16) | (u1.w & 0xffff0000u);
        #pragma unroll
        for (int mt = 0; mt < 4; ++mt) {
            int s8 = mt * 2 + kc;
            acc[mt] = MFMA16(W1h[s8], bh.v, acc[mt]);
            acc[mt] = MFMA16(W1h[s8], bl.v, acc[mt]);
            acc[mt] = MFMA16(W1l[s8], bh.v, acc[mt]);
        }
    }

    // ---- epilogue1: gelu, split, write tT ----
    #pragma unroll
    for (int mt = 0; mt < 4; ++mt) {
        const float* bp = b1v + mt * 16 + quad * 4;
        unsigned int pk[4];
        #pragma unroll
        for (int r = 0; r < 4; ++r) {
            float g = gelu_f(acc[mt][r] + bp[r]);
            pk[r] = bf16_split_pack(g);
        }
        int cg = mt * 4 + quad;
        unsigned int* dst = &tT[row * 64 + ((cg ^ lane15) << 2)];
        *(uint4*)dst = make_uint4(pk[0], pk[1], pk[2], pk[3]);
        acc[mt] = (f32x4){0.f, 0.f, 0.f, 0.f};
    }

    short8 W2h[8], W2l[8];
    #pragma unroll
    for (int s8 = 0; s8 < 8; ++s8) {
        const short8* p = (const short8*)(w2f + (((size_t)s8 * 64 + (t & 63)) << 4));
        W2h[s8] = p[0]; W2l[s8] = p[1];
    }

    __syncthreads();   // tT visible; also fences all waves past GEMM1 (sT dead -> oT may alias)

    // ---- GEMM2 ----
    #pragma unroll
    for (int kc = 0; kc < 2; ++kc) {
        int cg0 = kc * 8 + quad * 2;
        uint4 u0 = *(const uint4*)&tT[row * 64 + ((cg0 ^ lane15) << 2)];
        uint4 u1 = *(const uint4*)&tT[row * 64 + (((cg0 + 1) ^ lane15) << 2)];
        union { unsigned int w[4]; short8 v; } bh, bl;
        bh.w[0] = (u0.x & 0xffffu) | (u0.y << 16);
        bh.w[1] = (u0.z & 0xffffu) | (u0.w << 16);
        bh.w[2] = (u1.x & 0xffffu) | (u1.y << 16);
        bh.w[3] = (u1.z & 0xffffu) | (u1.w << 16);
        bl.w[0] = (u0.x >> 16) | (u0.y & 0xffff0000u);
        bl.w[1] = (u0.z >> 16) | (u0.w & 0xffff0000u);
        bl.w[2] = (u1.x >> 16) | (u1.y & 0xffff0000u);
        bl.w[3] = (u1.z >> 16) | (u1.w & 0xffff0000u);
        #pragma unroll
        for (int mt = 0; mt < 4; ++mt) {
            int s8 = mt * 2 + kc;
            acc[mt] = MFMA16(W2h[s8], bh.v, acc[mt]);
            acc[mt] = MFMA16(W2h[s8], bl.v, acc[mt]);
            acc[mt] = MFMA16(W2l[s8], bh.v, acc[mt]);
        }
    }

    // ---- epilogue2: gelu -> oT (f32, stride 68, aliases sT), then float4 h RMW ----
    #pragma unroll
    for (int mt = 0; mt < 4; ++mt) {
        const float* bp = b2v + mt * 16 + quad * 4;
        #pragma unroll
        for (int r = 0; r < 4; ++r) {
            int o = mt * 16 + quad * 4 + r;
            u.oT[o * 68 + row] = gelu_f(acc[mt][r] + bp[r]);
        }
    }
    __syncthreads();
    {
        int pix0 = (t & 15) * 4;
        int c0 = (t >> 4) * 4;                 // wave wv covers c = wv*16..+16
        #pragma unroll
        for (int i = 0; i < 4; ++i) {
            int c = c0 + i;
            float4 gv = *(const float4*)&u.oT[c * 68 + pix0];
            float* op = out + (size_t)c * NPIX + pixBase + pix0;
            float4 cur = *(const float4*)op;
            cur.x += gv.x; cur.y += gv.y; cur.z += gv.z; cur.w += gv.w;
            *(float4*)op = cur;
        }
    }
}

// Decoder
__global__ __launch_bounds__(256) void k_dec(const float* __restrict__ h, const float* __restrict__ Wd,
                                             const float* __restrict__ bd, float* __restrict__ out) {
    int pix = blockIdx.x * 256 + threadIdx.x;
    float acc = bd[0];
    #pragma unroll 8
    for (int c = 0; c < 64; ++c) acc += Wd[c] * h[(size_t)c * NPIX + pix];
    out[pix] = acc;
}

extern "C" void kernel_launch(void* const* d_in, const int* in_sizes, int n_in,
                              void* d_out, int out_size, void* d_ws, size_t ws_size,
                              hipStream_t stream) {
    (void)in_sizes; (void)n_in; (void)out_size; (void)ws_size;
    const float* u   = (const float*)d_in[0];
    const float* xc  = (const float*)d_in[1];
    const float* We  = (const float*)d_in[2];
    const float* be  = (const float*)d_in[3];
    const float* W1  = (const float*)d_in[4];
    const float* b1  = (const float*)d_in[5];
    const float* W2  = (const float*)d_in[6];
    const float* b2  = (const float*)d_in[7];
    const float* Are = (const float*)d_in[8];
    const float* Aim = (const float*)d_in[9];
    const float* Wd  = (const float*)d_in[10];
    const float* bd  = (const float*)d_in[11];

    // workspace layout (float units), ~165 MB
    float* ws  = (float*)d_ws;
    float* h   = ws;                            // 64 MB
    unsigned int* s = (unsigned int*)(h + (size_t)16777216);  // 64 MB (split-packed)
    float* Vf  = (float*)(s + (size_t)16777216); // 8 MB used: [2][64][32][512]
    float* VmH = Vf  + (size_t)4194304;         // 4 MB: [64][512][32]
    float* VmW = VmH + (size_t)1048576;         // 4 MB
    short* FbB = (short*)(VmW + 1048576);       // 64 KB
    short* GbF = FbB + 32768;                   // 64 KB
    short* Am  = GbF + 32768;                   // 6 MB: 65536 rec x 48 shorts
    short* Wpk = Am  + (size_t)65536 * 48;      // 128 KB

    k_bpack<<<16, 256, 0, stream>>>(FbB, GbF);
    k_afrag<<<256, 256, 0, stream>>>(Are, Aim, Am);
    k_wpack<<<16, 256, 0, stream>>>(W1, W2, Wpk);
    k_enc<<<1024, 256, 0, stream>>>(u, xc, We, be, h);

    const size_t aslab = (size_t)16 * 4 * 2 * 64 * 48;   // shorts per (l,ax)
    for (int l = 0; l < 4; ++l) {
        k_fwd_h<<<dim3(8, 64, 2), 256, 0, stream>>>(h, FbB, Vf);
        k_mix<<<256, 256, 0, stream>>>(Vf, Am + (size_t)(l * 2 + 0) * aslab, VmH);
        k_fwd_w<<<dim3(8, 64, 2), 256, 0, stream>>>(h, FbB, Vf);
        k_mix<<<256, 256, 0, stream>>>(Vf, Am + (size_t)(l * 2 + 1) * aslab, VmW);
        k_inv<<<dim3(8, 8, 64), 256, 0, stream>>>(VmW, VmH, GbF, s);
        k_ffn2m<<<4096, 256, 0, stream>>>(s, h,
                                          Wpk + (size_t)(l * 2 + 0) * 8192, b1 + (size_t)l * 64,
                                          Wpk + (size_t)(l * 2 + 1) * 8192, b2 + (size_t)l * 64);
    }
    k_dec<<<1024, 256, 0, stream>>>(h, Wd, bd, (float*)d_out);
}

// Round 7
// 582.148 us; speedup vs baseline: 1.7803x; 1.0600x over previous
//
#include <hip/hip_runtime.h>

#define NPIX (512*512)

typedef __attribute__((ext_vector_type(8))) short short8;   // 8 bf16 in 4 VGPRs
typedef __attribute__((ext_vector_type(4))) float f32x4;    // MFMA accumulator

#define MFMA16(A, B, C) __builtin_amdgcn_mfma_f32_16x16x32_bf16((A), (B), (C), 0, 0, 0)

// JAX gelu(approximate=True): x * sigmoid(2*sqrt(2/pi)*(x+0.044715x^3)); inf-safe.
__device__ __forceinline__ float gelu_f(float x) {
    return x / (1.0f + __expf(-1.5957691216057308f * (x + 0.044715f * x * x * x)));
}

// f32 -> bf16 bits (RNE)
__device__ __forceinline__ unsigned short bf16_rne(float x) {
    unsigned int b = __float_as_uint(x);
    unsigned int r = b + 0x7fffu + ((b >> 16) & 1u);
    return (unsigned short)(r >> 16);
}
__device__ __forceinline__ float bf16_tof(unsigned short h) {
    return __uint_as_float(((unsigned int)h) << 16);
}
// split x ~= hi + lo (each bf16); dropped cross term in 3-term MFMA ~2^-18 rel.
__device__ __forceinline__ unsigned int bf16_split_pack(float x) {
    unsigned short hi = bf16_rne(x);
    unsigned short lo = bf16_rne(x - bf16_tof(hi));
    return (unsigned int)hi | ((unsigned int)lo << 16);
}
__device__ __forceinline__ void split8(const float* x, short8& h, short8& l) {
    #pragma unroll
    for (int j = 0; j < 8; ++j) {
        unsigned short hi = bf16_rne(x[j]);
        h[j] = (short)hi;
        l[j] = (short)bf16_rne(x[j] - bf16_tof(hi));
    }
}

#define ASLAB ((size_t)16 * 4 * 2 * 64 * 48)   // shorts per (l,ax) in Am

// ---------------------------------------------------------------------------
// Merged setup: blocks 0..15 pack DFT basis tables, 16..31 pack FFN weights,
// 32..287 pack spectral A-weights. All independent; one launch.
// ---------------------------------------------------------------------------
__global__ __launch_bounds__(256) void k_setup(const float* __restrict__ W1, const float* __restrict__ W2,
                                               const float* __restrict__ Are, const float* __restrict__ Aim,
                                               short* __restrict__ FbB, short* __restrict__ GbF,
                                               short* __restrict__ Wpk, short* __restrict__ Am) {
    int b = blockIdx.x;
    int t = threadIdx.x;
    if (b < 16) {
        // ---- basis tables (split-bf16 frag records: 16 shorts = hi[8]|lo[8]) ----
        // FbB: record (kc<16, nt<2, lane): elem j = Fb[kc*32+quad*8+j][nt*16+l15]
        // GbF: record (tt<32, lane): elem j = Gb[tt*16+l15][quad*8+j]
        int id = b * 256 + t;                  // 4096 records
        int lane = id & 63;
        int quad = lane >> 4, l15 = lane & 15;
        short* dst;
        int n0, nstep, o0, ostep;
        float wscale = 1.0f;
        if (id < 2048) {
            int nt = (id >> 6) & 1, kc = id >> 7;
            dst = FbB + id * 16;
            n0 = kc * 32 + quad * 8; nstep = 1;
            o0 = nt * 16 + l15;      ostep = 0;
        } else {
            int id2 = id - 2048;
            dst = GbF + id2 * 16;
            int tt = id2 >> 6;
            n0 = tt * 16 + l15;      nstep = 0;
            o0 = quad * 8;           ostep = 1;
            wscale = 1.0f / 512.0f;
        }
        #pragma unroll
        for (int j = 0; j < 8; ++j) {
            int n = n0 + nstep * j;
            int o = o0 + ostep * j;
            int m = o >> 1, ri = o & 1;
            int k = (n * m) & 511;
            float sv, cv;
            sincosf(6.283185307179586f * (1.0f / 512.0f) * (float)k, &sv, &cv);
            float v = ri ? -sv : cv;
            if (id >= 2048) v *= (m == 0 ? 1.0f : 2.0f) * wscale;
            unsigned short hi = bf16_rne(v);
            dst[j]     = (short)hi;
            dst[8 + j] = (short)bf16_rne(v - bf16_tof(hi));
        }
    } else if (b < 32) {
        // ---- FFN weights -> MFMA A-frag layout, split-bf16 hi/lo ----
        int tid = (b - 16) * 256 + t;          // 4096 = 8 mat * 4 mt * 2 kc * 64 lanes
        int lane = tid & 63;
        int kc = (tid >> 6) & 1;
        int mt = (tid >> 7) & 3;
        int wg = tid >> 9;
        int layer = wg >> 1, which = wg & 1;
        const float* Wsrc = (which ? W2 : W1) + (size_t)layer * 4096;
        int o  = mt * 16 + (lane & 15);
        int c0 = kc * 32 + ((lane >> 4) & 3) * 8;
        short* dst = Wpk + (size_t)tid * 16;
        #pragma unroll
        for (int j = 0; j < 8; ++j) {
            float x = Wsrc[o * 64 + c0 + j];
            unsigned short hi = bf16_rne(x);
            dst[j]     = (short)hi;
            dst[8 + j] = (short)bf16_rne(x - bf16_tof(hi));
        }
    } else {
        // ---- spectral A -> mix A-frag records of 48 shorts:
        // [Ar_h8|Ar_l8|Ai_h8|Ai_l8|An_h8|An_l8] (An = -Ai) ----
        int id = (b - 32) * 256 + t;           // 65536 records
        int lane = id & 63;
        int kc  = (id >> 6) & 1;
        int mt  = (id >> 7) & 3;
        int m   = (id >> 9) & 15;
        int lax = id >> 13;
        int l = lax >> 1, ax = lax & 1;
        int o  = mt * 16 + (lane & 15);
        int i0 = kc * 32 + ((lane >> 4) & 3) * 8;
        short* dst = Am + (size_t)id * 48;
        #pragma unroll
        for (int j = 0; j < 8; ++j) {
            size_t src = (((size_t)(l * 64 + o) * 64 + (i0 + j)) * 16 + m) * 2 + ax;
            float ar = Are[src], ai = Aim[src];
            unsigned short hh;
            hh = bf16_rne(ar);  dst[j]      = (short)hh; dst[8 + j]  = (short)bf16_rne(ar - bf16_tof(hh));
            hh = bf16_rne(ai);  dst[16 + j] = (short)hh; dst[24 + j] = (short)bf16_rne(ai - bf16_tof(hh));
            hh = bf16_rne(-ai); dst[32 + j] = (short)hh; dst[40 + j] = (short)bf16_rne(-ai - bf16_tof(hh));
        }
    }
}

// Encoder
__global__ __launch_bounds__(256) void k_enc(const float* __restrict__ u, const float* __restrict__ xc,
                                             const float* __restrict__ We, const float* __restrict__ be,
                                             float* __restrict__ h) {
    int pix = blockIdx.x * 256 + threadIdx.x;
    float x0 = xc[pix], x1 = xc[NPIX + pix], uu = u[pix];
    #pragma unroll 8
    for (int p = 0; p < 64; ++p) {
        h[(size_t)p * NPIX + pix] = We[p * 3] * x0 + We[p * 3 + 1] * x1 + We[p * 3 + 2] * uu + be[p];
    }
}

// ---------------------------------------------------------------------------
// Merged forward DFT, both axes, full K=512 per block (no partials):
//   axis 0 (H): VfH[p][o][w] = sum_y Fb[y][o]*h[p][y][w]   (B = h columns)
//   axis 1 (W): VfW[p][o][y] = sum_w Fb[w][o]*h[p][y][w]   (B = h rows)
// grid(8 ntile, 64 p, 2 axis), block 256; wave -> 16-n slice. Branch is
// block-uniform (axis), so no divergence.
// ---------------------------------------------------------------------------
__global__ __launch_bounds__(256) void k_fwd(const float* __restrict__ h, const short* __restrict__ FbB,
                                             float* __restrict__ VfH, float* __restrict__ VfW) {
    int t = threadIdx.x;
    int ntb = blockIdx.x, p = blockIdx.y, axis = blockIdx.z;
    int wv = t >> 6, lane = t & 63, quad = lane >> 4, l15 = lane & 15;
    int n = ntb * 64 + wv * 16 + l15;          // w for axis0, y for axis1
    f32x4 acc[2];
    acc[0] = (f32x4){0.f,0.f,0.f,0.f}; acc[1] = (f32x4){0.f,0.f,0.f,0.f};
    #pragma unroll 4
    for (int kc = 0; kc < 16; ++kc) {
        int kb = kc * 32 + quad * 8;
        float bv[8];
        if (axis == 0) {
            const float* hp = h + ((size_t)p * 512 + kb) * 512 + n;
            #pragma unroll
            for (int j = 0; j < 8; ++j) bv[j] = hp[(size_t)j * 512];
        } else {
            const float* hp = h + ((size_t)p * 512 + n) * 512 + kb;
            float4 x0 = *(const float4*)hp;
            float4 x1 = *(const float4*)(hp + 4);
            bv[0]=x0.x; bv[1]=x0.y; bv[2]=x0.z; bv[3]=x0.w;
            bv[4]=x1.x; bv[5]=x1.y; bv[6]=x1.z; bv[7]=x1.w;
        }
        short8 Bh, Bl; split8(bv, Bh, Bl);
        #pragma unroll
        for (int mt = 0; mt < 2; ++mt) {
            const short8* ap = (const short8*)(FbB + (((kc * 2 + mt) * 64 + lane) << 4));
            short8 Ah = ap[0], Al = ap[1];
            acc[mt] = MFMA16(Ah, Bh, acc[mt]);
            acc[mt] = MFMA16(Al, Bh, acc[mt]);
            acc[mt] = MFMA16(Ah, Bl, acc[mt]);
        }
    }
    float* vp = (axis ? VfW : VfH) + (size_t)p * 32 * 512;
    #pragma unroll
    for (int mt = 0; mt < 2; ++mt)
        #pragma unroll
        for (int r = 0; r < 4; ++r)
            vp[(size_t)(mt * 16 + quad * 4 + r) * 512 + n] = acc[mt][r];
}

// ---------------------------------------------------------------------------
// Merged mode mixing, both axes: D_re = Ar.Br + An.Bi, D_im = Ar.Bi + Ai.Br.
// grid 512 (axis = bid>>8; m = bid&15, otile = (bid>>4)&15), block 256.
// ---------------------------------------------------------------------------
__global__ __launch_bounds__(256) void k_mix2(const float* __restrict__ VfH, const float* __restrict__ VfW,
                                              const short* __restrict__ AmL,
                                              float* __restrict__ VmH, float* __restrict__ VmW) {
    __shared__ unsigned int BT[2 * 64 * 33];
    int bid = blockIdx.x;
    int axis = bid >> 8;
    int m  = bid & 15;
    int ot = (bid >> 4) & 15;
    const float* Vf = axis ? VfW : VfH;
    float* Vm = axis ? VmW : VmH;
    const short* Am = AmL + (size_t)axis * ASLAB;
    int t = threadIdx.x;
    #pragma unroll
    for (int it = 0; it < 16; ++it) {
        int idx = it * 256 + t;                // 4096 = 64 i x 32 oth x 2 ri
        int oth = idx & 31, ri = (idx >> 5) & 1, i = idx >> 6;
        float v = Vf[((size_t)i * 32 + m * 2 + ri) * 512 + ot * 32 + oth];
        BT[(ri * 64 + i) * 33 + oth] = bf16_split_pack(v);
    }
    __syncthreads();
    int wv = t >> 6, lane = t & 63, quad = lane >> 4, l15 = lane & 15;
    int nt = wv & 1, mtp = wv >> 1;
    f32x4 aR[2], aI[2];
    aR[0]=(f32x4){0.f,0.f,0.f,0.f}; aR[1]=aR[0]; aI[0]=aR[0]; aI[1]=aR[0];
    #pragma unroll
    for (int kc = 0; kc < 2; ++kc) {
        short8 Brh, Brl, Bih, Bil;
        #pragma unroll
        for (int j = 0; j < 8; ++j) {
            int i = kc * 32 + quad * 8 + j;
            unsigned int br = BT[i * 33 + nt * 16 + l15];
            unsigned int bi = BT[(64 + i) * 33 + nt * 16 + l15];
            Brh[j] = (short)(br & 0xffffu); Brl[j] = (short)(br >> 16);
            Bih[j] = (short)(bi & 0xffffu); Bil[j] = (short)(bi >> 16);
        }
        #pragma unroll
        for (int mi = 0; mi < 2; ++mi) {
            int mt = mtp * 2 + mi;
            const short8* ap = (const short8*)(Am + ((size_t)(((m * 4 + mt) * 2 + kc) * 64 + lane)) * 48);
            short8 Arh = ap[0], Arl = ap[1], Aih = ap[2], Ail = ap[3], Anh = ap[4], Anl = ap[5];
            aR[mi] = MFMA16(Arh, Brh, aR[mi]);
            aR[mi] = MFMA16(Arl, Brh, aR[mi]);
            aR[mi] = MFMA16(Arh, Brl, aR[mi]);
            aR[mi] = MFMA16(Anh, Bih, aR[mi]);
            aR[mi] = MFMA16(Anl, Bih, aR[mi]);
            aR[mi] = MFMA16(Anh, Bil, aR[mi]);
            aI[mi] = MFMA16(Arh, Bih, aI[mi]);
            aI[mi] = MFMA16(Arl, Bih, aI[mi]);
            aI[mi] = MFMA16(Arh, Bil, aI[mi]);
            aI[mi] = MFMA16(Aih, Brh, aI[mi]);
            aI[mi] = MFMA16(Ail, Brh, aI[mi]);
            aI[mi] = MFMA16(Aih, Brl, aI[mi]);
        }
    }
    int oth = ot * 32 + nt * 16 + l15;
    #pragma unroll
    for (int mi = 0; mi < 2; ++mi) {
        int o = (mtp * 2 + mi) * 16 + quad * 4;
        #pragma unroll
        for (int r = 0; r < 4; ++r) {
            float2 v; v.x = aR[mi][r]; v.y = aI[mi][r];
            *(float2*)(Vm + ((size_t)(o + r) * 512 + oth) * 32 + m * 2) = v;
        }
    }
}

// ---------------------------------------------------------------------------
// Fused inverse DFT (both axes) -> s (SPLIT-PACKED u32: hi-bf16 | lo-bf16<<16).
// grid(8 wt, 8 yt, 64 p), block 256.
// ---------------------------------------------------------------------------
__global__ __launch_bounds__(256) void k_inv(const float* __restrict__ VmW, const float* __restrict__ VmH,
                                             const short* __restrict__ GbF, unsigned int* __restrict__ s) {
    int t = threadIdx.x;
    int wt = blockIdx.x, yt = blockIdx.y, p = blockIdx.z;
    int wv = t >> 6, lane = t & 63, quad = lane >> 4, l15 = lane & 15;
    int ys = yt * 64 + wv * 16;
    const float* a2p = VmW + ((size_t)p * 512 + ys + l15) * 32 + quad * 8;
    float av[8];
    {
        float4 x0 = *(const float4*)a2p;
        float4 x1 = *(const float4*)(a2p + 4);
        av[0]=x0.x; av[1]=x0.y; av[2]=x0.z; av[3]=x0.w;
        av[4]=x1.x; av[5]=x1.y; av[6]=x1.z; av[7]=x1.w;
    }
    short8 A2h, A2l; split8(av, A2h, A2l);
    const short8* g1 = (const short8*)(GbF + (((yt * 4 + wv) * 64 + lane) << 4));
    short8 A1h = g1[0], A1l = g1[1];
    #pragma unroll
    for (int nt = 0; nt < 4; ++nt) {
        int wb = wt * 64 + nt * 16;
        const float* b1p = VmH + ((size_t)p * 512 + wb + l15) * 32 + quad * 8;
        float bv[8];
        float4 x0 = *(const float4*)b1p;
        float4 x1 = *(const float4*)(b1p + 4);
        bv[0]=x0.x; bv[1]=x0.y; bv[2]=x0.z; bv[3]=x0.w;
        bv[4]=x1.x; bv[5]=x1.y; bv[6]=x1.z; bv[7]=x1.w;
        short8 B1h, B1l; split8(bv, B1h, B1l);
        const short8* g2 = (const short8*)(GbF + (((wt * 4 + nt) * 64 + lane) << 4));
        short8 B2h = g2[0], B2l = g2[1];
        f32x4 acc = (f32x4){0.f,0.f,0.f,0.f};
        acc = MFMA16(A1h, B1h, acc);
        acc = MFMA16(A1l, B1h, acc);
        acc = MFMA16(A1h, B1l, acc);
        acc = MFMA16(A2h, B2h, acc);
        acc = MFMA16(A2l, B2h, acc);
        acc = MFMA16(A2h, B2l, acc);
        #pragma unroll
        for (int r = 0; r < 4; ++r)
            s[((size_t)p * 512 + ys + quad * 4 + r) * 512 + wb + l15] = bf16_split_pack(acc[r]);
    }
}

// ---------------------------------------------------------------------------
// MFMA FFN: h[o][pix] += gelu(W2.gelu(W1.s+b1)+b2). s arrives pre-split-packed.
// oT aliases sT (union); LDS 33792 B -> 4 blocks/CU.
// ---------------------------------------------------------------------------
union FfnSmem {
    unsigned int sT[64 * 64];   // 16384 B, staging + GEMM1 B-operand
    float oT[64 * 68];          // 17408 B, epilogue2 transpose tile
};

__global__ __launch_bounds__(256, 4) void k_ffn2m(const unsigned int* __restrict__ in, float* __restrict__ out,
                                                  const short* __restrict__ w1f, const float* __restrict__ b1v,
                                                  const short* __restrict__ w2f, const float* __restrict__ b2v) {
    __shared__ __align__(16) FfnSmem u;
    __shared__ __align__(16) unsigned int tT[64 * 64];
    int t = threadIdx.x;
    int pixBase = blockIdx.x * 64;
    int lane15 = t & 15;
    int quad   = (t >> 4) & 3;
    int wv     = t >> 6;
    int row    = wv * 16 + lane15;

    {
        int pp = t & 63;
        int cq = wv;
        for (int q = 0; q < 4; ++q) {
            int cbase = q * 16 + cq * 4;
            unsigned int pk[4];
            #pragma unroll
            for (int i = 0; i < 4; ++i)
                pk[i] = in[(size_t)(cbase + i) * NPIX + pixBase + pp];
            int cg = cbase >> 2;
            unsigned int* dst = &u.sT[pp * 64 + (((cg ^ (pp & 15)) << 2))];
            *(uint4*)dst = make_uint4(pk[0], pk[1], pk[2], pk[3]);
        }
    }

    short8 W1h[8], W1l[8];
    #pragma unroll
    for (int s8 = 0; s8 < 8; ++s8) {
        const short8* p = (const short8*)(w1f + (((size_t)s8 * 64 + (t & 63)) << 4));
        W1h[s8] = p[0]; W1l[s8] = p[1];
    }

    f32x4 acc[4];
    #pragma unroll
    for (int mt = 0; mt < 4; ++mt) acc[mt] = (f32x4){0.f, 0.f, 0.f, 0.f};

    __syncthreads();

    // ---- GEMM1 ----
    #pragma unroll
    for (int kc = 0; kc < 2; ++kc) {
        int cg0 = kc * 8 + quad * 2;
        uint4 u0 = *(const uint4*)&u.sT[row * 64 + ((cg0 ^ lane15) << 2)];
        uint4 u1 = *(const uint4*)&u.sT[row * 64 + (((cg0 + 1) ^ lane15) << 2)];
        union { unsigned int w[4]; short8 v; } bh, bl;
        bh.w[0] = (u0.x & 0xffffu) | (u0.y << 16);
        bh.w[1] = (u0.z & 0xffffu) | (u0.w << 16);
        bh.w[2] = (u1.x & 0xffffu) | (u1.y << 16);
        bh.w[3] = (u1.z & 0xffffu) | (u1.w << 16);
        bl.w[0] = (u0.x >> 16) | (u0.y & 0xffff0000u);
        bl.w[1] = (u0.z >> 16) | (u0.w & 0xffff0000u);
        bl.w[2] = (u1.x >> 16) | (u1.y & 0xffff0000u);
        bl.w[3] = (u1.z >> 16) | (u1.w & 0xffff0000u);
        #pragma unroll
        for (int mt = 0; mt < 4; ++mt) {
            int s8 = mt * 2 + kc;
            acc[mt] = MFMA16(W1h[s8], bh.v, acc[mt]);
            acc[mt] = MFMA16(W1h[s8], bl.v, acc[mt]);
            acc[mt] = MFMA16(W1l[s8], bh.v, acc[mt]);
        }
    }

    // ---- epilogue1: gelu, split, write tT ----
    #pragma unroll
    for (int mt = 0; mt < 4; ++mt) {
        const float* bp = b1v + mt * 16 + quad * 4;
        unsigned int pk[4];
        #pragma unroll
        for (int r = 0; r < 4; ++r) {
            float g = gelu_f(acc[mt][r] + bp[r]);
            pk[r] = bf16_split_pack(g);
        }
        int cg = mt * 4 + quad;
        unsigned int* dst = &tT[row * 64 + ((cg ^ lane15) << 2)];
        *(uint4*)dst = make_uint4(pk[0], pk[1], pk[2], pk[3]);
        acc[mt] = (f32x4){0.f, 0.f, 0.f, 0.f};
    }

    short8 W2h[8], W2l[8];
    #pragma unroll
    for (int s8 = 0; s8 < 8; ++s8) {
        const short8* p = (const short8*)(w2f + (((size_t)s8 * 64 + (t & 63)) << 4));
        W2h[s8] = p[0]; W2l[s8] = p[1];
    }

    __syncthreads();   // tT visible; also fences all waves past GEMM1 (sT dead -> oT may alias)

    // ---- GEMM2 ----
    #pragma unroll
    for (int kc = 0; kc < 2; ++kc) {
        int cg0 = kc * 8 + quad * 2;
        uint4 u0 = *(const uint4*)&tT[row * 64 + ((cg0 ^ lane15) << 2)];
        uint4 u1 = *(const uint4*)&tT[row * 64 + (((cg0 + 1) ^ lane15) << 2)];
        union { unsigned int w[4]; short8 v; } bh, bl;
        bh.w[0] = (u0.x & 0xffffu) | (u0.y << 16);
        bh.w[1] = (u0.z & 0xffffu) | (u0.w << 16);
        bh.w[2] = (u1.x & 0xffffu) | (u1.y << 16);
        bh.w[3] = (u1.z & 0xffffu) | (u1.w << 16);
        bl.w[0] = (u0.x >> 16) | (u0.y & 0xffff0000u);
        bl.w[1] = (u0.z >> 16) | (u0.w & 0xffff0000u);
        bl.w[2] = (u1.x >> 16) | (u1.y & 0xffff0000u);
        bl.w[3] = (u1.z >> 16) | (u1.w & 0xffff0000u);
        #pragma unroll
        for (int mt = 0; mt < 4; ++mt) {
            int s8 = mt * 2 + kc;
            acc[mt] = MFMA16(W2h[s8], bh.v, acc[mt]);
            acc[mt] = MFMA16(W2h[s8], bl.v, acc[mt]);
            acc[mt] = MFMA16(W2l[s8], bh.v, acc[mt]);
        }
    }

    // ---- epilogue2: gelu -> oT (f32, stride 68, aliases sT), then float4 h RMW ----
    #pragma unroll
    for (int mt = 0; mt < 4; ++mt) {
        const float* bp = b2v + mt * 16 + quad * 4;
        #pragma unroll
        for (int r = 0; r < 4; ++r) {
            int o = mt * 16 + quad * 4 + r;
            u.oT[o * 68 + row] = gelu_f(acc[mt][r] + bp[r]);
        }
    }
    __syncthreads();
    {
        int pix0 = (t & 15) * 4;
        int c0 = (t >> 4) * 4;
        #pragma unroll
        for (int i = 0; i < 4; ++i) {
            int c = c0 + i;
            float4 gv = *(const float4*)&u.oT[c * 68 + pix0];
            float* op = out + (size_t)c * NPIX + pixBase + pix0;
            float4 cur = *(const float4*)op;
            cur.x += gv.x; cur.y += gv.y; cur.z += gv.z; cur.w += gv.w;
            *(float4*)op = cur;
        }
    }
}

// Decoder
__global__ __launch_bounds__(256) void k_dec(const float* __restrict__ h, const float* __restrict__ Wd,
                                             const float* __restrict__ bd, float* __restrict__ out) {
    int pix = blockIdx.x * 256 + threadIdx.x;
    float acc = bd[0];
    #pragma unroll 8
    for (int c = 0; c < 64; ++c) acc += Wd[c] * h[(size_t)c * NPIX + pix];
    out[pix] = acc;
}

extern "C" void kernel_launch(void* const* d_in, const int* in_sizes, int n_in,
                              void* d_out, int out_size, void* d_ws, size_t ws_size,
                              hipStream_t stream) {
    (void)in_sizes; (void)n_in; (void)out_size; (void)ws_size;
    const float* u   = (const float*)d_in[0];
    const float* xc  = (const float*)d_in[1];
    const float* We  = (const float*)d_in[2];
    const float* be  = (const float*)d_in[3];
    const float* W1  = (const float*)d_in[4];
    const float* b1  = (const float*)d_in[5];
    const float* W2  = (const float*)d_in[6];
    const float* b2  = (const float*)d_in[7];
    const float* Are = (const float*)d_in[8];
    const float* Aim = (const float*)d_in[9];
    const float* Wd  = (const float*)d_in[10];
    const float* bd  = (const float*)d_in[11];

    // workspace layout (float units), ~155 MB
    float* ws  = (float*)d_ws;
    float* h   = ws;                            // 64 MB
    unsigned int* s = (unsigned int*)(h + (size_t)16777216);  // 64 MB (split-packed)
    float* VfH = (float*)(s + (size_t)16777216); // 4 MB: [64][32][512]
    float* VfW = VfH + (size_t)1048576;         // 4 MB
    float* VmH = VfW + (size_t)1048576;         // 4 MB: [64][512][32]
    float* VmW = VmH + (size_t)1048576;         // 4 MB
    short* FbB = (short*)(VmW + 1048576);       // 64 KB
    short* GbF = FbB + 32768;                   // 64 KB
    short* Am  = GbF + 32768;                   // 6 MB: 65536 rec x 48 shorts
    short* Wpk = Am  + (size_t)65536 * 48;      // 128 KB

    k_setup<<<288, 256, 0, stream>>>(W1, W2, Are, Aim, FbB, GbF, Wpk, Am);
    k_enc<<<1024, 256, 0, stream>>>(u, xc, We, be, h);

    for (int l = 0; l < 4; ++l) {
        k_fwd<<<dim3(8, 64, 2), 256, 0, stream>>>(h, FbB, VfH, VfW);
        k_mix2<<<512, 256, 0, stream>>>(VfH, VfW, Am + (size_t)(l * 2) * ASLAB, VmH, VmW);
        k_inv<<<dim3(8, 8, 64), 256, 0, stream>>>(VmW, VmH, GbF, s);
        k_ffn2m<<<4096, 256, 0, stream>>>(s, h,
                                          Wpk + (size_t)(l * 2 + 0) * 8192, b1 + (size_t)l * 64,
                                          Wpk + (size_t)(l * 2 + 1) * 8192, b2 + (size_t)l * 64);
    }
    k_dec<<<1024, 256, 0, stream>>>(h, Wd, bd, (float*)d_out);
}

// Round 8
// 554.366 us; speedup vs baseline: 1.8696x; 1.0501x over previous
//
#include <hip/hip_runtime.h>

#define NPIX (512*512)

typedef __attribute__((ext_vector_type(8))) short short8;   // 8 bf16 in 4 VGPRs
typedef __attribute__((ext_vector_type(4))) float f32x4;    // MFMA accumulator

#define MFMA16(A, B, C) __builtin_amdgcn_mfma_f32_16x16x32_bf16((A), (B), (C), 0, 0, 0)

// JAX gelu(approximate=True): x * sigmoid(2*sqrt(2/pi)*(x+0.044715x^3)); inf-safe.
__device__ __forceinline__ float gelu_f(float x) {
    return x / (1.0f + __expf(-1.5957691216057308f * (x + 0.044715f * x * x * x)));
}

// f32 -> bf16 bits (RNE)
__device__ __forceinline__ unsigned short bf16_rne(float x) {
    unsigned int b = __float_as_uint(x);
    unsigned int r = b + 0x7fffu + ((b >> 16) & 1u);
    return (unsigned short)(r >> 16);
}
__device__ __forceinline__ float bf16_tof(unsigned short h) {
    return __uint_as_float(((unsigned int)h) << 16);
}
// split x ~= hi + lo (each bf16); dropped cross term in 3-term MFMA ~2^-18 rel.
__device__ __forceinline__ unsigned int bf16_split_pack(float x) {
    unsigned short hi = bf16_rne(x);
    unsigned short lo = bf16_rne(x - bf16_tof(hi));
    return (unsigned int)hi | ((unsigned int)lo << 16);
}
__device__ __forceinline__ void split8(const float* x, short8& h, short8& l) {
    #pragma unroll
    for (int j = 0; j < 8; ++j) {
        unsigned short hi = bf16_rne(x[j]);
        h[j] = (short)hi;
        l[j] = (short)bf16_rne(x[j] - bf16_tof(hi));
    }
}

#define ASLAB ((size_t)16 * 4 * 2 * 64 * 48)   // shorts per (l,ax) in Am

// ---------------------------------------------------------------------------
// Merged setup: blocks 0..15 pack DFT basis tables, 16..31 pack FFN weights,
// 32..287 pack spectral A-weights. All independent; one launch.
// ---------------------------------------------------------------------------
__global__ __launch_bounds__(256) void k_setup(const float* __restrict__ W1, const float* __restrict__ W2,
                                               const float* __restrict__ Are, const float* __restrict__ Aim,
                                               short* __restrict__ FbB, short* __restrict__ GbF,
                                               short* __restrict__ Wpk, short* __restrict__ Am) {
    int b = blockIdx.x;
    int t = threadIdx.x;
    if (b < 16) {
        // FbB: record (kc<16, nt<2, lane): elem j = Fb[kc*32+quad*8+j][nt*16+l15]
        // GbF: record (tt<32, lane): elem j = Gb[tt*16+l15][quad*8+j]
        int id = b * 256 + t;
        int lane = id & 63;
        int quad = lane >> 4, l15 = lane & 15;
        short* dst;
        int n0, nstep, o0, ostep;
        float wscale = 1.0f;
        if (id < 2048) {
            int nt = (id >> 6) & 1, kc = id >> 7;
            dst = FbB + id * 16;
            n0 = kc * 32 + quad * 8; nstep = 1;
            o0 = nt * 16 + l15;      ostep = 0;
        } else {
            int id2 = id - 2048;
            dst = GbF + id2 * 16;
            int tt = id2 >> 6;
            n0 = tt * 16 + l15;      nstep = 0;
            o0 = quad * 8;           ostep = 1;
            wscale = 1.0f / 512.0f;
        }
        #pragma unroll
        for (int j = 0; j < 8; ++j) {
            int n = n0 + nstep * j;
            int o = o0 + ostep * j;
            int m = o >> 1, ri = o & 1;
            int k = (n * m) & 511;
            float sv, cv;
            sincosf(6.283185307179586f * (1.0f / 512.0f) * (float)k, &sv, &cv);
            float v = ri ? -sv : cv;
            if (id >= 2048) v *= (m == 0 ? 1.0f : 2.0f) * wscale;
            unsigned short hi = bf16_rne(v);
            dst[j]     = (short)hi;
            dst[8 + j] = (short)bf16_rne(v - bf16_tof(hi));
        }
    } else if (b < 32) {
        int tid = (b - 16) * 256 + t;
        int lane = tid & 63;
        int kc = (tid >> 6) & 1;
        int mt = (tid >> 7) & 3;
        int wg = tid >> 9;
        int layer = wg >> 1, which = wg & 1;
        const float* Wsrc = (which ? W2 : W1) + (size_t)layer * 4096;
        int o  = mt * 16 + (lane & 15);
        int c0 = kc * 32 + ((lane >> 4) & 3) * 8;
        short* dst = Wpk + (size_t)tid * 16;
        #pragma unroll
        for (int j = 0; j < 8; ++j) {
            float x = Wsrc[o * 64 + c0 + j];
            unsigned short hi = bf16_rne(x);
            dst[j]     = (short)hi;
            dst[8 + j] = (short)bf16_rne(x - bf16_tof(hi));
        }
    } else {
        // spectral A -> mix A-frag records of 48 shorts: [Ar_h8|Ar_l8|Ai_h8|Ai_l8|An_h8|An_l8]
        int id = (b - 32) * 256 + t;
        int lane = id & 63;
        int kc  = (id >> 6) & 1;
        int mt  = (id >> 7) & 3;
        int m   = (id >> 9) & 15;
        int lax = id >> 13;
        int l = lax >> 1, ax = lax & 1;
        int o  = mt * 16 + (lane & 15);
        int i0 = kc * 32 + ((lane >> 4) & 3) * 8;
        short* dst = Am + (size_t)id * 48;
        #pragma unroll
        for (int j = 0; j < 8; ++j) {
            size_t src = (((size_t)(l * 64 + o) * 64 + (i0 + j)) * 16 + m) * 2 + ax;
            float ar = Are[src], ai = Aim[src];
            unsigned short hh;
            hh = bf16_rne(ar);  dst[j]      = (short)hh; dst[8 + j]  = (short)bf16_rne(ar - bf16_tof(hh));
            hh = bf16_rne(ai);  dst[16 + j] = (short)hh; dst[24 + j] = (short)bf16_rne(ai - bf16_tof(hh));
            hh = bf16_rne(-ai); dst[32 + j] = (short)hh; dst[40 + j] = (short)bf16_rne(-ai - bf16_tof(hh));
        }
    }
}

// Encoder
__global__ __launch_bounds__(256) void k_enc(const float* __restrict__ u, const float* __restrict__ xc,
                                             const float* __restrict__ We, const float* __restrict__ be,
                                             float* __restrict__ h) {
    int pix = blockIdx.x * 256 + threadIdx.x;
    float x0 = xc[pix], x1 = xc[NPIX + pix], uu = u[pix];
    #pragma unroll 8
    for (int p = 0; p < 64; ++p) {
        h[(size_t)p * NPIX + pix] = We[p * 3] * x0 + We[p * 3 + 1] * x1 + We[p * 3 + 2] * uu + be[p];
    }
}

// ---------------------------------------------------------------------------
// Merged forward DFT, both axes, full K=512 per block:
//   axis 0 (H): VfH[p][o][w] = sum_y Fb[y][o]*h[p][y][w]   (B = h columns)
//   axis 1 (W): VfW[p][o][y] = sum_w Fb[w][o]*h[p][y][w]   (B = h rows)
// grid(8 ntile, 64 p, 2 axis), block 256; axis branch is block-uniform.
// ---------------------------------------------------------------------------
__global__ __launch_bounds__(256) void k_fwd(const float* __restrict__ h, const short* __restrict__ FbB,
                                             float* __restrict__ VfH, float* __restrict__ VfW) {
    int t = threadIdx.x;
    int ntb = blockIdx.x, p = blockIdx.y, axis = blockIdx.z;
    int wv = t >> 6, lane = t & 63, quad = lane >> 4, l15 = lane & 15;
    int n = ntb * 64 + wv * 16 + l15;
    f32x4 acc[2];
    acc[0] = (f32x4){0.f,0.f,0.f,0.f}; acc[1] = (f32x4){0.f,0.f,0.f,0.f};
    #pragma unroll 4
    for (int kc = 0; kc < 16; ++kc) {
        int kb = kc * 32 + quad * 8;
        float bv[8];
        if (axis == 0) {
            const float* hp = h + ((size_t)p * 512 + kb) * 512 + n;
            #pragma unroll
            for (int j = 0; j < 8; ++j) bv[j] = hp[(size_t)j * 512];
        } else {
            const float* hp = h + ((size_t)p * 512 + n) * 512 + kb;
            float4 x0 = *(const float4*)hp;
            float4 x1 = *(const float4*)(hp + 4);
            bv[0]=x0.x; bv[1]=x0.y; bv[2]=x0.z; bv[3]=x0.w;
            bv[4]=x1.x; bv[5]=x1.y; bv[6]=x1.z; bv[7]=x1.w;
        }
        short8 Bh, Bl; split8(bv, Bh, Bl);
        #pragma unroll
        for (int mt = 0; mt < 2; ++mt) {
            const short8* ap = (const short8*)(FbB + (((kc * 2 + mt) * 64 + lane) << 4));
            short8 Ah = ap[0], Al = ap[1];
            acc[mt] = MFMA16(Ah, Bh, acc[mt]);
            acc[mt] = MFMA16(Al, Bh, acc[mt]);
            acc[mt] = MFMA16(Ah, Bl, acc[mt]);
        }
    }
    float* vp = (axis ? VfW : VfH) + (size_t)p * 32 * 512;
    #pragma unroll
    for (int mt = 0; mt < 2; ++mt)
        #pragma unroll
        for (int r = 0; r < 4; ++r)
            vp[(size_t)(mt * 16 + quad * 4 + r) * 512 + n] = acc[mt][r];
}

// ---------------------------------------------------------------------------
// Merged mode mixing, both axes: D_re = Ar.Br + An.Bi, D_im = Ar.Bi + Ai.Br.
// grid 512 (axis = bid>>8; m = bid&15, otile = (bid>>4)&15), block 256.
// ---------------------------------------------------------------------------
__global__ __launch_bounds__(256) void k_mix2(const float* __restrict__ VfH, const float* __restrict__ VfW,
                                              const short* __restrict__ AmL,
                                              float* __restrict__ VmH, float* __restrict__ VmW) {
    __shared__ unsigned int BT[2 * 64 * 33];
    int bid = blockIdx.x;
    int axis = bid >> 8;
    int m  = bid & 15;
    int ot = (bid >> 4) & 15;
    const float* Vf = axis ? VfW : VfH;
    float* Vm = axis ? VmW : VmH;
    const short* Am = AmL + (size_t)axis * ASLAB;
    int t = threadIdx.x;
    #pragma unroll
    for (int it = 0; it < 16; ++it) {
        int idx = it * 256 + t;
        int oth = idx & 31, ri = (idx >> 5) & 1, i = idx >> 6;
        float v = Vf[((size_t)i * 32 + m * 2 + ri) * 512 + ot * 32 + oth];
        BT[(ri * 64 + i) * 33 + oth] = bf16_split_pack(v);
    }
    __syncthreads();
    int wv = t >> 6, lane = t & 63, quad = lane >> 4, l15 = lane & 15;
    int nt = wv & 1, mtp = wv >> 1;
    f32x4 aR[2], aI[2];
    aR[0]=(f32x4){0.f,0.f,0.f,0.f}; aR[1]=aR[0]; aI[0]=aR[0]; aI[1]=aR[0];
    #pragma unroll
    for (int kc = 0; kc < 2; ++kc) {
        short8 Brh, Brl, Bih, Bil;
        #pragma unroll
        for (int j = 0; j < 8; ++j) {
            int i = kc * 32 + quad * 8 + j;
            unsigned int br = BT[i * 33 + nt * 16 + l15];
            unsigned int bi = BT[(64 + i) * 33 + nt * 16 + l15];
            Brh[j] = (short)(br & 0xffffu); Brl[j] = (short)(br >> 16);
            Bih[j] = (short)(bi & 0xffffu); Bil[j] = (short)(bi >> 16);
        }
        #pragma unroll
        for (int mi = 0; mi < 2; ++mi) {
            int mt = mtp * 2 + mi;
            const short8* ap = (const short8*)(Am + ((size_t)(((m * 4 + mt) * 2 + kc) * 64 + lane)) * 48);
            short8 Arh = ap[0], Arl = ap[1], Aih = ap[2], Ail = ap[3], Anh = ap[4], Anl = ap[5];
            aR[mi] = MFMA16(Arh, Brh, aR[mi]);
            aR[mi] = MFMA16(Arl, Brh, aR[mi]);
            aR[mi] = MFMA16(Arh, Brl, aR[mi]);
            aR[mi] = MFMA16(Anh, Bih, aR[mi]);
            aR[mi] = MFMA16(Anl, Bih, aR[mi]);
            aR[mi] = MFMA16(Anh, Bil, aR[mi]);
            aI[mi] = MFMA16(Arh, Bih, aI[mi]);
            aI[mi] = MFMA16(Arl, Bih, aI[mi]);
            aI[mi] = MFMA16(Arh, Bil, aI[mi]);
            aI[mi] = MFMA16(Aih, Brh, aI[mi]);
            aI[mi] = MFMA16(Ail, Brh, aI[mi]);
            aI[mi] = MFMA16(Aih, Brl, aI[mi]);
        }
    }
    int oth = ot * 32 + nt * 16 + l15;
    #pragma unroll
    for (int mi = 0; mi < 2; ++mi) {
        int o = (mtp * 2 + mi) * 16 + quad * 4;
        #pragma unroll
        for (int r = 0; r < 4; ++r) {
            float2 v; v.x = aR[mi][r]; v.y = aI[mi][r];
            *(float2*)(Vm + ((size_t)(o + r) * 512 + oth) * 32 + m * 2) = v;
        }
    }
}

// ---------------------------------------------------------------------------
// Fused inverse DFT (both axes) -> s as PLAIN BF16 (2 B): s only feeds FFN
// GEMM1 whose W-side stays split; s quantization is ~2^-9 rel on the layer
// increment only (residual stream stays f32).
// grid(8 wt, 8 yt, 64 p), block 256.
// ---------------------------------------------------------------------------
__global__ __launch_bounds__(256) void k_inv(const float* __restrict__ VmW, const float* __restrict__ VmH,
                                             const short* __restrict__ GbF, unsigned short* __restrict__ s) {
    int t = threadIdx.x;
    int wt = blockIdx.x, yt = blockIdx.y, p = blockIdx.z;
    int wv = t >> 6, lane = t & 63, quad = lane >> 4, l15 = lane & 15;
    int ys = yt * 64 + wv * 16;
    const float* a2p = VmW + ((size_t)p * 512 + ys + l15) * 32 + quad * 8;
    float av[8];
    {
        float4 x0 = *(const float4*)a2p;
        float4 x1 = *(const float4*)(a2p + 4);
        av[0]=x0.x; av[1]=x0.y; av[2]=x0.z; av[3]=x0.w;
        av[4]=x1.x; av[5]=x1.y; av[6]=x1.z; av[7]=x1.w;
    }
    short8 A2h, A2l; split8(av, A2h, A2l);
    const short8* g1 = (const short8*)(GbF + (((yt * 4 + wv) * 64 + lane) << 4));
    short8 A1h = g1[0], A1l = g1[1];
    #pragma unroll
    for (int nt = 0; nt < 4; ++nt) {
        int wb = wt * 64 + nt * 16;
        const float* b1p = VmH + ((size_t)p * 512 + wb + l15) * 32 + quad * 8;
        float bv[8];
        float4 x0 = *(const float4*)b1p;
        float4 x1 = *(const float4*)(b1p + 4);
        bv[0]=x0.x; bv[1]=x0.y; bv[2]=x0.z; bv[3]=x0.w;
        bv[4]=x1.x; bv[5]=x1.y; bv[6]=x1.z; bv[7]=x1.w;
        short8 B1h, B1l; split8(bv, B1h, B1l);
        const short8* g2 = (const short8*)(GbF + (((wt * 4 + nt) * 64 + lane) << 4));
        short8 B2h = g2[0], B2l = g2[1];
        f32x4 acc = (f32x4){0.f,0.f,0.f,0.f};
        acc = MFMA16(A1h, B1h, acc);
        acc = MFMA16(A1l, B1h, acc);
        acc = MFMA16(A1h, B1l, acc);
        acc = MFMA16(A2h, B2h, acc);
        acc = MFMA16(A2l, B2h, acc);
        acc = MFMA16(A2h, B2l, acc);
        #pragma unroll
        for (int r = 0; r < 4; ++r)
            s[((size_t)p * 512 + ys + quad * 4 + r) * 512 + wb + l15] = bf16_rne(acc[r]);
    }
}

// ---------------------------------------------------------------------------
// MFMA FFN: h[o][pix] += gelu(W2.gelu(W1.s+b1)+b2). s arrives as bf16 [c][pix].
// Staging: thread (k=t>>3 channel-pair, po=t&7 pixel-oct) loads 2 uint4 (8 pix
// of ch 2k and 2k+1), zips to per-pixel channel pairs, writes 8 u32 to
// sB[pix*33 + k] (stride 33: bank = pix+k -> staging writes 2-way/free, frag
// b32 reads <=4-way). GEMM1 B-frag = 4 b32 reads reinterpreted as short8
// (channel pairs already in order) -> 2-term MFMA (Wh.B + Wl.B).
// oT aliases sB; LDS total 33792 B -> 4 blocks/CU.
// ---------------------------------------------------------------------------
union FfnSmem {
    unsigned int sB[64 * 33];   // 8448 B, staged bf16 s tile [pix][ch-pair]
    float oT[64 * 68];          // 17408 B, epilogue2 transpose tile
};

__global__ __launch_bounds__(256, 4) void k_ffn2m(const unsigned short* __restrict__ in, float* __restrict__ out,
                                                  const short* __restrict__ w1f, const float* __restrict__ b1v,
                                                  const short* __restrict__ w2f, const float* __restrict__ b2v) {
    __shared__ __align__(16) FfnSmem u;
    __shared__ __align__(16) unsigned int tT[64 * 64];
    int t = threadIdx.x;
    int pixBase = blockIdx.x * 64;
    int lane15 = t & 15;
    int quad   = (t >> 4) & 3;
    int wv     = t >> 6;
    int row    = wv * 16 + lane15;

    // ---- stage bf16 s tile: 2 coalesced uint4 loads -> zip -> sB ----
    {
        int k  = t >> 3;                       // channel pair 0..31
        int po = t & 7;                        // pixel oct
        const uint4* r0 = (const uint4*)(in + (size_t)(2 * k) * NPIX + pixBase) + po;
        const uint4* r1 = (const uint4*)(in + (size_t)(2 * k + 1) * NPIX + pixBase) + po;
        uint4 a = *r0, b = *r1;
        unsigned int aw[4] = {a.x, a.y, a.z, a.w};
        unsigned int bw[4] = {b.x, b.y, b.z, b.w};
        #pragma unroll
        for (int i = 0; i < 4; ++i) {
            int pix = po * 8 + 2 * i;
            u.sB[pix * 33 + k]       = (aw[i] & 0xffffu) | (bw[i] << 16);
            u.sB[(pix + 1) * 33 + k] = (aw[i] >> 16) | (bw[i] & 0xffff0000u);
        }
    }

    short8 W1h[8], W1l[8];
    #pragma unroll
    for (int s8 = 0; s8 < 8; ++s8) {
        const short8* p = (const short8*)(w1f + (((size_t)s8 * 64 + (t & 63)) << 4));
        W1h[s8] = p[0]; W1l[s8] = p[1];
    }

    f32x4 acc[4];
    #pragma unroll
    for (int mt = 0; mt < 4; ++mt) acc[mt] = (f32x4){0.f, 0.f, 0.f, 0.f};

    __syncthreads();

    // ---- GEMM1: 2-term (s is bf16) ----
    #pragma unroll
    for (int kc = 0; kc < 2; ++kc) {
        union { unsigned int w[4]; short8 v; } bb;
        #pragma unroll
        for (int i = 0; i < 4; ++i)
            bb.w[i] = u.sB[row * 33 + kc * 16 + quad * 4 + i];
        #pragma unroll
        for (int mt = 0; mt < 4; ++mt) {
            int s8 = mt * 2 + kc;
            acc[mt] = MFMA16(W1h[s8], bb.v, acc[mt]);
            acc[mt] = MFMA16(W1l[s8], bb.v, acc[mt]);
        }
    }

    // ---- epilogue1: gelu, split, write tT ----
    #pragma unroll
    for (int mt = 0; mt < 4; ++mt) {
        const float* bp = b1v + mt * 16 + quad * 4;
        unsigned int pk[4];
        #pragma unroll
        for (int r = 0; r < 4; ++r) {
            float g = gelu_f(acc[mt][r] + bp[r]);
            pk[r] = bf16_split_pack(g);
        }
        int cg = mt * 4 + quad;
        unsigned int* dst = &tT[row * 64 + ((cg ^ lane15) << 2)];
        *(uint4*)dst = make_uint4(pk[0], pk[1], pk[2], pk[3]);
        acc[mt] = (f32x4){0.f, 0.f, 0.f, 0.f};
    }

    short8 W2h[8], W2l[8];
    #pragma unroll
    for (int s8 = 0; s8 < 8; ++s8) {
        const short8* p = (const short8*)(w2f + (((size_t)s8 * 64 + (t & 63)) << 4));
        W2h[s8] = p[0]; W2l[s8] = p[1];
    }

    __syncthreads();   // tT visible; also fences all waves past GEMM1 (sB dead -> oT may alias)

    // ---- GEMM2: 3-term (t stays split) ----
    #pragma unroll
    for (int kc = 0; kc < 2; ++kc) {
        int cg0 = kc * 8 + quad * 2;
        uint4 u0 = *(const uint4*)&tT[row * 64 + ((cg0 ^ lane15) << 2)];
        uint4 u1 = *(const uint4*)&tT[row * 64 + (((cg0 + 1) ^ lane15) << 2)];
        union { unsigned int w[4]; short8 v; } bh, bl;
        bh.w[0] = (u0.x & 0xffffu) | (u0.y << 16);
        bh.w[1] = (u0.z & 0xffffu) | (u0.w << 16);
        bh.w[2] = (u1.x & 0xffffu) | (u1.y << 16);
        bh.w[3] = (u1.z & 0xffffu) | (u1.w << 16);
        bl.w[0] = (u0.x >> 16) | (u0.y & 0xffff0000u);
        bl.w[1] = (u0.z >> 16) | (u0.w & 0xffff0000u);
        bl.w[2] = (u1.x >> 16) | (u1.y & 0xffff0000u);
        bl.w[3] = (u1.z >> 16) | (u1.w & 0xffff0000u);
        #pragma unroll
        for (int mt = 0; mt < 4; ++mt) {
            int s8 = mt * 2 + kc;
            acc[mt] = MFMA16(W2h[s8], bh.v, acc[mt]);
            acc[mt] = MFMA16(W2h[s8], bl.v, acc[mt]);
            acc[mt] = MFMA16(W2l[s8], bh.v, acc[mt]);
        }
    }

    // ---- epilogue2: gelu -> oT (f32, stride 68, aliases sB), then float4 h RMW ----
    #pragma unroll
    for (int mt = 0; mt < 4; ++mt) {
        const float* bp = b2v + mt * 16 + quad * 4;
        #pragma unroll
        for (int r = 0; r < 4; ++r) {
            int o = mt * 16 + quad * 4 + r;
            u.oT[o * 68 + row] = gelu_f(acc[mt][r] + bp[r]);
        }
    }
    __syncthreads();
    {
        int pix0 = (t & 15) * 4;
        int c0 = (t >> 4) * 4;
        #pragma unroll
        for (int i = 0; i < 4; ++i) {
            int c = c0 + i;
            float4 gv = *(const float4*)&u.oT[c * 68 + pix0];
            float* op = out + (size_t)c * NPIX + pixBase + pix0;
            float4 cur = *(const float4*)op;
            cur.x += gv.x; cur.y += gv.y; cur.z += gv.z; cur.w += gv.w;
            *(float4*)op = cur;
        }
    }
}

// Decoder
__global__ __launch_bounds__(256) void k_dec(const float* __restrict__ h, const float* __restrict__ Wd,
                                             const float* __restrict__ bd, float* __restrict__ out) {
    int pix = blockIdx.x * 256 + threadIdx.x;
    float acc = bd[0];
    #pragma unroll 8
    for (int c = 0; c < 64; ++c) acc += Wd[c] * h[(size_t)c * NPIX + pix];
    out[pix] = acc;
}

extern "C" void kernel_launch(void* const* d_in, const int* in_sizes, int n_in,
                              void* d_out, int out_size, void* d_ws, size_t ws_size,
                              hipStream_t stream) {
    (void)in_sizes; (void)n_in; (void)out_size; (void)ws_size;
    const float* u   = (const float*)d_in[0];
    const float* xc  = (const float*)d_in[1];
    const float* We  = (const float*)d_in[2];
    const float* be  = (const float*)d_in[3];
    const float* W1  = (const float*)d_in[4];
    const float* b1  = (const float*)d_in[5];
    const float* W2  = (const float*)d_in[6];
    const float* b2  = (const float*)d_in[7];
    const float* Are = (const float*)d_in[8];
    const float* Aim = (const float*)d_in[9];
    const float* Wd  = (const float*)d_in[10];
    const float* bd  = (const float*)d_in[11];

    // workspace layout (float units), ~125 MB used
    float* ws  = (float*)d_ws;
    float* h   = ws;                            // 64 MB
    unsigned short* s = (unsigned short*)(h + (size_t)16777216);  // 32 MB (bf16), 64 MB slot
    float* VfH = (float*)((char*)s + (size_t)67108864); // 4 MB: [64][32][512]
    float* VfW = VfH + (size_t)1048576;         // 4 MB
    float* VmH = VfW + (size_t)1048576;         // 4 MB: [64][512][32]
    float* VmW = VmH + (size_t)1048576;         // 4 MB
    short* FbB = (short*)(VmW + 1048576);       // 64 KB
    short* GbF = FbB + 32768;                   // 64 KB
    short* Am  = GbF + 32768;                   // 6 MB: 65536 rec x 48 shorts
    short* Wpk = Am  + (size_t)65536 * 48;      // 128 KB

    k_setup<<<288, 256, 0, stream>>>(W1, W2, Are, Aim, FbB, GbF, Wpk, Am);
    k_enc<<<1024, 256, 0, stream>>>(u, xc, We, be, h);

    for (int l = 0; l < 4; ++l) {
        k_fwd<<<dim3(8, 64, 2), 256, 0, stream>>>(h, FbB, VfH, VfW);
        k_mix2<<<512, 256, 0, stream>>>(VfH, VfW, Am + (size_t)(l * 2) * ASLAB, VmH, VmW);
        k_inv<<<dim3(8, 8, 64), 256, 0, stream>>>(VmW, VmH, GbF, s);
        k_ffn2m<<<4096, 256, 0, stream>>>(s, h,
                                          Wpk + (size_t)(l * 2 + 0) * 8192, b1 + (size_t)l * 64,
                                          Wpk + (size_t)(l * 2 + 1) * 8192, b2 + (size_t)l * 64);
    }
    k_dec<<<1024, 256, 0, stream>>>(h, Wd, bd, (float*)d_out);
}